// Round 10
// baseline (293.095 us; speedup 1.0000x reference)
//
#include <hip/hip_runtime.h>

// ---------------------------------------------------------------------------
// Euler Attention forward, MI355X gfx950 — ROUND 26 (r25 resubmit).
// r25 bench: infra failure ("container failed twice"), same signature as r22
// which cleared on resubmit. Kernel re-audit: barriers uniform, vmcnt ledger
// exact, no buffer hazard (PV is reg-only), tiles 0..31 covered once, no
// forced VGPR cap. Resubmitting v11 unchanged:
//  - attn v11: cross-tile PV pipeline (T15): PV(t-1) deferred past barrier-2
//    of iter t, ping-pong reg sets paA/bvA <-> paB/bvB (static indices).
//  - prep_cast absorbs cast_transpose_w.
// GEMMs unchanged from r20/r24.
// ---------------------------------------------------------------------------

typedef unsigned short bf16_t;
typedef short frag_ab __attribute__((ext_vector_type(8)));   // 8 bf16 = 4 VGPRs
typedef float frag_cd __attribute__((ext_vector_type(4)));   // 4 fp32 acc
typedef float f32x16 __attribute__((ext_vector_type(16)));   // 32x32 acc

#define BB 2
#define LL 2048
#define DD 1024
#define HH 16
#define DH 64

#define QSCALE 0.18033688f     // 0.125 * log2(e)
#define EOFF  -17.3123404907f  // -12 * log2(e)

__device__ __forceinline__ float b2f(bf16_t u) {
  union { unsigned int i; float f; } c; c.i = ((unsigned int)u) << 16; return c.f;
}
__device__ __forceinline__ bf16_t f2b(float f) {
  union { float f; unsigned int i; } c; c.f = f;
  unsigned int r = c.i + 0x7fffu + ((c.i >> 16) & 1u);
  return (bf16_t)(r >> 16);
}
__device__ __forceinline__ unsigned int fbits(float f) {
  union { float f; unsigned int i; } c; c.f = f; return c.i;
}
__device__ __forceinline__ float waveMax(float v) {
#pragma unroll
  for (int m = 32; m > 0; m >>= 1) v = fmaxf(v, __shfl_xor(v, m));
  return v;
}
__device__ __forceinline__ float waveSum(float v) {
#pragma unroll
  for (int m = 32; m > 0; m >>= 1) v += __shfl_xor(v, m);
  return v;
}

// async global->LDS, 16B/lane; lds base wave-uniform (HW adds lane*16)
__device__ __forceinline__ void gll16(const bf16_t* g, bf16_t* l) {
  __builtin_amdgcn_global_load_lds(
      (const __attribute__((address_space(1))) void*)g,
      (__attribute__((address_space(3))) void*)l, 16, 0, 0);
}

// conflict-free tile read: [32 super-rows of 256B][16 slots of 16B]
// (row, chunk) at super=row>>1, slot=(((row&1)<<3)+chunk)^((row>>1)&15)
__device__ __forceinline__ frag_ab ld_cf(const bf16_t* base, int row, int chunk) {
  const int sup = row >> 1;
  const int t = (((row & 1) << 3) | chunk) ^ (sup & 15);
  return *(const frag_ab*)((const char*)base + sup * 256 + t * 16);
}

// pack 8 fp32 -> 8 bf16 (truncating) into an A-frag
__device__ __forceinline__ frag_ab pack8(const float* p) {
  union { unsigned int u[4]; frag_ab f; } x;
  x.u[0] = __builtin_amdgcn_perm(fbits(p[1]), fbits(p[0]), 0x07060302u);
  x.u[1] = __builtin_amdgcn_perm(fbits(p[3]), fbits(p[2]), 0x07060302u);
  x.u[2] = __builtin_amdgcn_perm(fbits(p[5]), fbits(p[4]), 0x07060302u);
  x.u[3] = __builtin_amdgcn_perm(fbits(p[7]), fbits(p[6]), 0x07060302u);
  return x.f;
}

// merged prep: X cast (blocks 0..4095), Wv cast (4096..5119),
// Wd cast (5120..6143), xmean zero (6144), Wq/Wk cast+transpose (6145..6656)
__global__ __launch_bounds__(256) void prep_cast(const float* __restrict__ X,
                                                 const float* __restrict__ Wv,
                                                 const float* __restrict__ Wd,
                                                 const float* __restrict__ Wq,
                                                 const float* __restrict__ Wk,
                                                 bf16_t* __restrict__ Xb,
                                                 bf16_t* __restrict__ Wvb,
                                                 bf16_t* __restrict__ Wdb,
                                                 bf16_t* __restrict__ WqT,
                                                 bf16_t* __restrict__ WkT,
                                                 float* __restrict__ xmean) {
  const int bid = blockIdx.x;
  const int tid = threadIdx.x;
  __shared__ bf16_t T[64][72];
  if (bid >= 6145) {                    // cast+transpose Wq/Wk, 64x64 tiles
    const int t = bid - 6145;           // 0..511: (16, 16, 2)
    const float* W = (t >> 8) ? Wk : Wq;
    bf16_t* WT = (t >> 8) ? WkT : WqT;
    const int i0 = (t & 15) * 64, m0 = ((t >> 4) & 15) * 64;
#pragma unroll
    for (int it = 0; it < 4; ++it) {
      const int idx = tid + it * 256;
      const int r = idx >> 4, c4 = (idx & 15) * 4;
      float4 v = *(const float4*)&W[(size_t)(i0 + r) * DD + m0 + c4];
      T[c4 + 0][r] = f2b(v.x);
      T[c4 + 1][r] = f2b(v.y);
      T[c4 + 2][r] = f2b(v.z);
      T[c4 + 3][r] = f2b(v.w);
    }
    __syncthreads();
#pragma unroll
    for (int it = 0; it < 2; ++it) {
      const int idx = tid + it * 256;
      const int r = idx >> 3, seg = idx & 7;
      *(uint4*)&WT[(size_t)(m0 + r) * DD + i0 + seg * 8] = *(const uint4*)&T[r][seg * 8];
    }
    return;
  }
  if (bid == 6144) {
    for (int i = tid; i < BB * DD; i += 256) xmean[i] = 0.f;
    return;
  }
  const float* in;
  bf16_t* out;
  int i;
  if (bid < 4096)      { in = X;  out = Xb;  i = bid * 256 + tid; }
  else if (bid < 5120) { in = Wv; out = Wvb; i = (bid - 4096) * 256 + tid; }
  else                 { in = Wd; out = Wdb; i = (bid - 5120) * 256 + tid; }
  float4 v = ((const float4*)in)[i];
  ushort4 o;
  o.x = f2b(v.x); o.y = f2b(v.y); o.z = f2b(v.z); o.w = f2b(v.w);
  ((ushort4*)out)[i] = o;
}

// ---------------------------------------------------------------------------
struct GemmB { const bf16_t* A; const bf16_t* Bm; const float* bias; float* Cf; bf16_t* Cb; };
struct GemmArgs { GemmB gb[6]; };

// 128x128 tile MFMA GEMM (4 waves 2x2, each 64x64) — dbuf + counted vmcnt
__global__ __launch_bounds__(256) void gemm128(GemmArgs ga, int M, int N, int K) {
  const GemmB g = ga.gb[blockIdx.z];
  const int bm = blockIdx.y * 128, bn = blockIdx.x * 128;
  __shared__ bf16_t As[2][128][32];
  __shared__ bf16_t Bs[2][128][32];
  const int tid = threadIdx.x;
  const int lane = tid & 63, w = tid >> 6;
  const int quad = lane >> 4, l16 = lane & 15;
  const int wm = (w >> 1) * 64, wn = (w & 1) * 64;
  const int wbase = w << 9;

  frag_cd acc[4][4];
#pragma unroll
  for (int i = 0; i < 4; ++i)
#pragma unroll
    for (int j = 0; j < 4; ++j)
#pragma unroll
      for (int r = 0; r < 4; ++r) acc[i][j][r] = 0.f;

  const int r0 = tid >> 2, s0 = (tid & 3) * 8;
  const int r1 = (tid + 256) >> 2, s1 = ((tid + 256) & 3) * 8;
  const size_t aoff0 = (size_t)(bm + r0) * K + s0;
  const size_t aoff1 = (size_t)(bm + r1) * K + s1;
  const size_t boff0 = (size_t)(bn + r0) * K + s0;
  const size_t boff1 = (size_t)(bn + r1) * K + s1;

  auto STAGE = [&](int buf, int k0) {
    bf16_t* Af = &As[buf][0][0];
    bf16_t* Bf = &Bs[buf][0][0];
    gll16(g.A + aoff0 + k0, Af + wbase);
    gll16(g.A + aoff1 + k0, Af + 2048 + wbase);
    gll16(g.Bm + boff0 + k0, Bf + wbase);
    gll16(g.Bm + boff1 + k0, Bf + 2048 + wbase);
  };

  STAGE(0, 0);
  int cur = 0;
  for (int k0 = 0; k0 < K; k0 += 32) {
    if (k0 + 32 < K) {
      STAGE(cur ^ 1, k0 + 32);                      // 4 next-tile loads in flight
      asm volatile("s_waitcnt vmcnt(4)" ::: "memory");  // cur tile landed
    } else {
      asm volatile("s_waitcnt vmcnt(0)" ::: "memory");
    }
    __builtin_amdgcn_s_barrier();
    frag_ab af[4], bfr[4];
#pragma unroll
    for (int i = 0; i < 4; ++i) {
      af[i]  = *(const frag_ab*)&As[cur][wm + i * 16 + l16][quad * 8];
      bfr[i] = *(const frag_ab*)&Bs[cur][wn + i * 16 + l16][quad * 8];
    }
#pragma unroll
    for (int i = 0; i < 4; ++i)
#pragma unroll
      for (int j = 0; j < 4; ++j)
        acc[i][j] = __builtin_amdgcn_mfma_f32_16x16x32_bf16(af[i], bfr[j], acc[i][j], 0, 0, 0);
    __builtin_amdgcn_s_barrier();
    cur ^= 1;
  }

#pragma unroll
  for (int i = 0; i < 4; ++i) {
#pragma unroll
    for (int r = 0; r < 4; ++r) {
      const int row = bm + wm + i * 16 + quad * 4 + r;
#pragma unroll
      for (int j = 0; j < 4; ++j) {
        const int col = bn + wn + j * 16 + l16;
        float v = acc[i][j][r];
        if (g.bias) v += g.bias[col];
        if (g.Cf) g.Cf[(size_t)row * N + col] = v;
        if (g.Cb) g.Cb[(size_t)row * N + col] = f2b(v);
      }
    }
  }
}

// 64x64 tile MFMA GEMM (4 waves 2x2, each 32x32) — dbuf + counted vmcnt
__global__ __launch_bounds__(256) void gemm64x64(GemmArgs ga, int M, int N, int K) {
  const GemmB g = ga.gb[blockIdx.z];
  const int bm = blockIdx.y * 64, bn = blockIdx.x * 64;
  __shared__ bf16_t As[2][64][32];
  __shared__ bf16_t Bs[2][64][32];
  const int tid = threadIdx.x;
  const int lane = tid & 63, w = tid >> 6;
  const int quad = lane >> 4, l16 = lane & 15;
  const int wm = (w >> 1) * 32, wn = (w & 1) * 32;
  const int wbase = w << 9;

  frag_cd acc[2][2];
#pragma unroll
  for (int i = 0; i < 2; ++i)
#pragma unroll
    for (int j = 0; j < 2; ++j)
#pragma unroll
      for (int r = 0; r < 4; ++r) acc[i][j][r] = 0.f;

  const int r0 = tid >> 2, s0 = (tid & 3) * 8;
  const size_t aoff0 = (size_t)(bm + r0) * K + s0;
  const size_t boff0 = (size_t)(bn + r0) * K + s0;

  auto STAGE = [&](int buf, int k0) {
    gll16(g.A + aoff0 + k0, &As[buf][0][0] + wbase);
    gll16(g.Bm + boff0 + k0, &Bs[buf][0][0] + wbase);
  };

  STAGE(0, 0);
  int cur = 0;
  for (int k0 = 0; k0 < K; k0 += 32) {
    if (k0 + 32 < K) {
      STAGE(cur ^ 1, k0 + 32);                      // 2 next-tile loads in flight
      asm volatile("s_waitcnt vmcnt(2)" ::: "memory");  // cur tile landed
    } else {
      asm volatile("s_waitcnt vmcnt(0)" ::: "memory");
    }
    __builtin_amdgcn_s_barrier();
    frag_ab af[2], bfr[2];
#pragma unroll
    for (int i = 0; i < 2; ++i) {
      af[i]  = *(const frag_ab*)&As[cur][wm + i * 16 + l16][quad * 8];
      bfr[i] = *(const frag_ab*)&Bs[cur][wn + i * 16 + l16][quad * 8];
    }
#pragma unroll
    for (int i = 0; i < 2; ++i)
#pragma unroll
      for (int j = 0; j < 2; ++j)
        acc[i][j] = __builtin_amdgcn_mfma_f32_16x16x32_bf16(af[i], bfr[j], acc[i][j], 0, 0, 0);
    __builtin_amdgcn_s_barrier();
    cur ^= 1;
  }

#pragma unroll
  for (int i = 0; i < 2; ++i) {
#pragma unroll
    for (int r = 0; r < 4; ++r) {
      const int row = bm + wm + i * 16 + quad * 4 + r;
#pragma unroll
      for (int j = 0; j < 2; ++j) {
        const int col = bn + wn + j * 16 + l16;
        float v = acc[i][j][r];
        if (g.bias) v += g.bias[col];
        if (g.Cf) g.Cf[(size_t)row * N + col] = v;
        if (g.Cb) g.Cb[(size_t)row * N + col] = f2b(v);
      }
    }
  }
}

// xmean[b][d] = mean over L of X[b][l][d]
__global__ __launch_bounds__(256) void xmean_kernel(const float* __restrict__ X,
                                                    float* __restrict__ xmean) {
  const int d = blockIdx.x * 256 + threadIdx.x;
  const int b = blockIdx.z;
  const int l0 = blockIdx.y * 64;
  float s = 0.f;
  for (int l = l0; l < l0 + 64; ++l)
    s += X[((size_t)b * LL + l) * DD + d];
  atomicAdd(&xmean[b * DD + d], s * (1.f / (float)LL));
}

// scores: one wave per output
__global__ __launch_bounds__(256) void scores_gemm(const float* __restrict__ xmean,
                                                   const float* __restrict__ Wq,
                                                   const float* __restrict__ bq,
                                                   const float* __restrict__ Wk,
                                                   const float* __restrict__ bk,
                                                   float* __restrict__ scores) {
  const int w = threadIdx.x >> 6, lane = threadIdx.x & 63;
  const int idx = blockIdx.x * 4 + w;
  const int t = idx >> 11, b = (idx >> 10) & 1, i = idx & 1023;
  const float* W = t ? Wk : Wq;
  const float* bias = t ? bk : bq;
  const float* xm = xmean + b * DD;
  float sum = 0.f;
#pragma unroll
  for (int k = 0; k < 4; ++k) {
    float4 wv = *(const float4*)&W[(size_t)i * DD + k * 256 + lane * 4];
    float4 xv = *(const float4*)&xm[k * 256 + lane * 4];
    sum += wv.x * xv.x + wv.y * xv.y + wv.z * xv.z + wv.w * xv.w;
  }
  sum = waveSum(sum);
  if (lane == 0) scores[idx] = sum + bias[i];
}

// Bsum: 16 blocks, float4 LDS reads
__global__ __launch_bounds__(256) void bsum_kernel(const float* __restrict__ scores,
                                                   float* __restrict__ bsum) {
  __shared__ float sc[DD];
  const int z = blockIdx.x, jb = blockIdx.y, tid = threadIdx.x;
#pragma unroll
  for (int s = 0; s < 4; ++s) sc[tid + s * 256] = scores[z * DD + tid + s * 256];
  __syncthreads();
  const int j = jb * 256 + tid;
  const float si = sc[j];
  float s = 0.f;
  for (int m = 0; m < DD; m += 4) {
    float4 v = *(const float4*)&sc[m];
    s += fabsf(si - v.x) + fabsf(si - v.y) + fabsf(si - v.z) + fabsf(si - v.w);
  }
  bsum[z * DD + j] = s;
}

// P row + folded bias'
__global__ __launch_bounds__(256) void p_kernel(const float* __restrict__ scores,
                                                const float* __restrict__ bsum,
                                                const float* __restrict__ bq,
                                                const float* __restrict__ bk,
                                                bf16_t* __restrict__ Pq,
                                                bf16_t* __restrict__ Pk,
                                                float* __restrict__ bias4) {
  const int i = blockIdx.x;
  const int z = blockIdx.y;
  const int t = z >> 1, b = z & 1;
  const float* sc = scores + z * DD;
  const float* bs = bsum + z * DD;
  const float* bias = t ? bk : bq;
  const float scal = 1023.f - 2.f * (float)i;
  const int tid = threadIdx.x;
  __shared__ float redA[4], redB[4], redC[4];

  float lg[4], bb[4];
  float mx = -1e30f;
#pragma unroll
  for (int s = 0; s < 4; ++s) {
    const int j = tid + s * 256;
    lg[s] = sc[j] * scal - bs[j];
    bb[s] = bias[j];
    mx = fmaxf(mx, lg[s]);
  }
  mx = waveMax(mx);
  if ((tid & 63) == 0) redA[tid >> 6] = mx;
  __syncthreads();
  const float M = fmaxf(fmaxf(redA[0], redA[1]), fmaxf(redA[2], redA[3]));
  float sum = 0.f, dot = 0.f;
#pragma unroll
  for (int s = 0; s < 4; ++s) {
    lg[s] = __expf(lg[s] - M);
    sum += lg[s];
    dot += lg[s] * bb[s];
  }
  sum = waveSum(sum); dot = waveSum(dot);
  if ((tid & 63) == 0) { redB[tid >> 6] = sum; redC[tid >> 6] = dot; }
  __syncthreads();
  const float inv = 1.f / (redB[0] + redB[1] + redB[2] + redB[3]);
  bf16_t* P = (t ? Pk : Pq) + ((size_t)b << 20) + (size_t)i * DD;
#pragma unroll
  for (int s = 0; s < 4; ++s) P[tid + s * 256] = f2b(lg[s] * inv);
  if (tid == 0)
    bias4[t * 2048 + b * 1024 + i] = (redC[0] + redC[1] + redC[2] + redC[3]) * inv;
}

// merged euler (blocks 0..16383, q scaled by QSCALE) + V transpose (16384..)
// V transpose applies the 32x32x16 k-slot permutation: within each 16-key
// block of L, output position order is [0-3, 8-11, 4-7, 12-15] (bit2<->bit3
// involution), so attn's PV B-frags read contiguous b128.
__global__ __launch_bounds__(256) void euler_transv(bf16_t* __restrict__ qs,
                                                    bf16_t* __restrict__ ks,
                                                    const float* __restrict__ delta,
                                                    const float* __restrict__ beul,
                                                    const float* __restrict__ lsc,
                                                    const bf16_t* __restrict__ vb,
                                                    bf16_t* __restrict__ vbT) {
  __shared__ bf16_t T[64][72];
  const int bid = blockIdx.x;
  const int tid = threadIdx.x;
  if (bid < 16384) {
    const int isq = (bid < 8192);
    unsigned int* buf = (unsigned int*)(isq ? qs : ks);
    const int idx = (isq ? bid : bid - 8192) * 256 + tid;
    const int c = idx & 511;
    const size_t n = idx >> 9;
    const unsigned int u = buf[n * 512 + c];
    const float r = b2f((bf16_t)(u & 0xffffu));
    const float p = b2f((bf16_t)(u >> 16));
    float lam = sqrtf(r * r + p * p + 1e-6f);
    float th = atan2f(p, r) * delta[c];
    if (isq) th += beul[c];
    lam *= __expf(fminf(fmaxf(lsc[c], -5.f), 5.f));
    if (isq) lam *= QSCALE;    // fold attention scale into q (q only feeds attn)
    float sn, cs;
    __sincosf(th, &sn, &cs);
    buf[n * 512 + c] = ((unsigned int)f2b(lam * sn) << 16) | (unsigned int)f2b(lam * cs);
    return;
  }
  const int tb = bid - 16384;                 // 0..1023: (32, 16, 2)
  const int l0 = (tb & 31) * 64, d0 = ((tb >> 5) & 15) * 64, b = tb >> 9;
  for (int i = tid; i < 512; i += 256) {
    const int r = i >> 3, seg = i & 7;
    uint4 v = *(const uint4*)&vb[((size_t)b * LL + l0 + r) * DD + d0 + seg * 8];
    const bf16_t* vs = (const bf16_t*)&v;
#pragma unroll
    for (int j = 0; j < 8; ++j) T[seg * 8 + j][r] = vs[j];
  }
  __syncthreads();
  for (int i = tid; i < 512; i += 256) {
    const int r = i >> 3, seg = i & 7;
    // permuted gather: positions seg*8..+8 hold keys {base..base+3, base+8..+11}
    const int kb = (seg >> 1) * 16 + (seg & 1) * 4;
    uint2 lo = *(const uint2*)&T[r][kb];
    uint2 hi2 = *(const uint2*)&T[r][kb + 8];
    uint4 o; o.x = lo.x; o.y = lo.y; o.z = hi2.x; o.w = hi2.y;
    *(uint4*)&vbT[((size_t)b * DD + d0 + r) * LL + l0 + seg * 8] = o;
  }
}

// ---------------------------------------------------------------------------
// Flash attention v11: 512 blocks x 256 thr, 4 waves x 32 queries (32x32x16).
// r24 structure (P in regs, key-permuted V, conflict-free LDS layout,
// dbuf + vmcnt(4) + two barriers) + cross-tile PV pipeline: PV(t-1) runs
// after barrier-2 of iter t, overlapping next iter's STAGE/barrier wait.
// Ping-pong register sets via explicit 2x unroll (static indices only).
// ---------------------------------------------------------------------------
__global__ __launch_bounds__(256) void attn_kernel(const bf16_t* __restrict__ Q,
                                                   const bf16_t* __restrict__ Kt,
                                                   const bf16_t* __restrict__ VT,
                                                   bf16_t* __restrict__ O) {
  const int bid = blockIdx.x;
  const int swz = (bid & 7) * 64 + (bid >> 3);    // bijective, 64 blocks/XCD
  const int g = swz >> 4;                         // 4 bh-groups per XCD
  const int qt = swz & 15;
  const int b = g >> 4, h = g & 15;
  const int q0 = qt * 128;
  const int tid = threadIdx.x, w = tid >> 6, lane = tid & 63;
  const int hi = lane >> 5, l31 = lane & 31;

  __shared__ bf16_t Ks[2][64 * 64];
  __shared__ bf16_t Vs[2][64 * 64];

  const size_t base = (size_t)b * LL * DD + (size_t)h * DH;
  const size_t vtb = (size_t)(b * DD + h * DH) * LL;

  // Q fragments straight to registers (q pre-scaled by QSCALE at euler)
  frag_ab bq[4];
#pragma unroll
  for (int kd = 0; kd < 4; ++kd)
    bq[kd] = *(const frag_ab*)
        &Q[base + (size_t)(q0 + w * 32 + l31) * DD + kd * 16 + hi * 8];

  // constant ones-column B-frag: col 0 => lanes with l31==0 hold 8x 1.0
  frag_ab bone;
  {
    const short o = (l31 == 0) ? (short)0x3F80 : (short)0;
#pragma unroll
    for (int j = 0; j < 8; ++j) bone[j] = o;
  }

  f32x16 o_[2], l5;
#pragma unroll
  for (int i = 0; i < 16; ++i) { o_[0][i] = 0.f; o_[1][i] = 0.f; l5[i] = 0.f; }

  // STAGE decode for conflict-free layout (r24)
  const int sup_l = lane >> 4;
  const int sl15 = lane & 15;

  auto STAGE = [&](int buf, int kt) {
#pragma unroll
    for (int t = 0; t < 2; ++t) {
      const int supb = w * 8 + t * 4;
      const int sup = supb + sup_l;
      const int tt = sl15 ^ (sup & 15);
      const int row = sup * 2 + (tt >> 3);
      const int ch = tt & 7;
      gll16(Kt + base + (size_t)(kt * 64 + row) * DD + ch * 8,
            &Ks[buf][(w * 16 + t * 8) * 64]);
      gll16(VT + vtb + (size_t)row * LL + kt * 64 + ch * 8,
            &Vs[buf][(w * 16 + t * 8) * 64]);
    }
  };

  // QK phase: compute P A-frags + load V B-frags for tile in buffer `buf`
  auto QK = [&](int buf, frag_ab* pa, frag_ab* bv) {
    const bf16_t* Kb = Ks[buf];
    const bf16_t* Vb = Vs[buf];
#pragma unroll
    for (int s = 0; s < 2; ++s) {
      frag_ab ak[4];
#pragma unroll
      for (int kd = 0; kd < 4; ++kd)
        ak[kd] = ld_cf(Kb, s * 32 + l31, kd * 2 + hi);
      f32x16 z;
#pragma unroll
      for (int i = 0; i < 16; ++i) z[i] = EOFF;
#pragma unroll
      for (int kd = 0; kd < 4; ++kd)
        z = __builtin_amdgcn_mfma_f32_32x32x16_bf16(ak[kd], bq[kd], z, 0, 0, 0);
#pragma unroll
      for (int t = 0; t < 2; ++t) {
        float p[8];
#pragma unroll
        for (int j = 0; j < 8; ++j) p[j] = __builtin_amdgcn_exp2f(z[t * 8 + j]);
        pa[s * 2 + t] = pack8(p);
      }
    }
#pragma unroll
    for (int dt = 0; dt < 2; ++dt)
#pragma unroll
      for (int k = 0; k < 4; ++k)
        bv[dt * 4 + k] = ld_cf(Vb, dt * 32 + l31, k * 2 + hi);
  };

  // PV phase: pure-register MFMA (l + O accumulate)
  auto PV = [&](const frag_ab* pa, const frag_ab* bv) {
#pragma unroll
    for (int k = 0; k < 4; ++k)
      l5 = __builtin_amdgcn_mfma_f32_32x32x16_bf16(pa[k], bone, l5, 0, 0, 0);
#pragma unroll
    for (int dt = 0; dt < 2; ++dt)
#pragma unroll
      for (int k = 0; k < 4; ++k)
        o_[dt] = __builtin_amdgcn_mfma_f32_32x32x16_bf16(pa[k], bv[dt * 4 + k], o_[dt], 0, 0, 0);
  };

  frag_ab paA[4], bvA[8], paB[4], bvB[8];

  // iter 0 (buf 0): no deferred PV yet
  STAGE(0, 0);
  STAGE(1, 1);
  asm volatile("s_waitcnt vmcnt(4)" ::: "memory");
  __builtin_amdgcn_s_barrier();
  QK(0, paA, bvA);
  __builtin_amdgcn_s_barrier();

  // pairs: iters (kt, kt+1) for kt = 1,3,...,29
  for (int kt = 1; kt <= 29; kt += 2) {
    // iter kt (buf 1): QK into B, PV(A)
    STAGE(0, kt + 1);
    asm volatile("s_waitcnt vmcnt(4)" ::: "memory");
    __builtin_amdgcn_s_barrier();
    QK(1, paB, bvB);
    __builtin_amdgcn_s_barrier();
    PV(paA, bvA);
    // iter kt+1 (buf 0): QK into A, PV(B)
    STAGE(1, kt + 2);
    asm volatile("s_waitcnt vmcnt(4)" ::: "memory");
    __builtin_amdgcn_s_barrier();
    QK(0, paA, bvA);
    __builtin_amdgcn_s_barrier();
    PV(paB, bvB);
  }

  // iter 31 (buf 1): last tile, then drain both PV sets
  asm volatile("s_waitcnt vmcnt(0)" ::: "memory");
  __builtin_amdgcn_s_barrier();
  QK(1, paB, bvB);
  PV(paA, bvA);
  PV(paB, bvB);

  // l[q] lives at col 0 => lane hi*32, reg r (q = (r&3)+8*(r>>2)+4*hi)
  const int src = (lane >> 5) << 5;
  float lf[16];
#pragma unroll
  for (int r = 0; r < 16; ++r) lf[r] = 1.f / __shfl(l5[r], src);

#pragma unroll
  for (int dt = 0; dt < 2; ++dt)
#pragma unroll
    for (int r = 0; r < 16; ++r) {
      const int ql = (r & 3) + 8 * (r >> 2) + 4 * hi;
      O[base + (size_t)(q0 + w * 32 + ql) * DD + dt * 32 + l31] =
          f2b(o_[dt][r] * lf[r]);
    }
}

// layernorm(hidden(bf16) + X) * gamma + beta -> FP32 out
__global__ __launch_bounds__(256) void ln_kernel(const bf16_t* __restrict__ hidden,
                                                 const float* __restrict__ x0,
                                                 const float* __restrict__ gamma,
                                                 const float* __restrict__ beta,
                                                 float* __restrict__ out) {
  const int row = blockIdx.x;
  const int tid = threadIdx.x;
  __shared__ float red1[4], red2[4];
  float v[4];
  float s1 = 0.f, s2 = 0.f;
#pragma unroll
  for (int s = 0; s < 4; ++s) {
    const int c = tid + s * 256;
    const float x = b2f(hidden[(size_t)row * DD + c]) + x0[(size_t)row * DD + c];
    v[s] = x; s1 += x; s2 += x * x;
  }
  s1 = waveSum(s1); s2 = waveSum(s2);
  if ((tid & 63) == 0) { red1[tid >> 6] = s1; red2[tid >> 6] = s2; }
  __syncthreads();
  const float t1 = red1[0] + red1[1] + red1[2] + red1[3];
  const float t2 = red2[0] + red2[1] + red2[2] + red2[3];
  const float mu = t1 * (1.f / DD);
  const float var = t2 * (1.f / DD) - mu * mu;
  const float inv = rsqrtf(var + 1e-12f);
#pragma unroll
  for (int s = 0; s < 4; ++s) {
    const int c = tid + s * 256;
    out[(size_t)row * DD + c] = (v[s] - mu) * inv * gamma[c] + beta[c];
  }
}

// ---------------------------------------------------------------------------
extern "C" void kernel_launch(void* const* d_in, const int* in_sizes, int n_in,
                              void* d_out, int out_size, void* d_ws, size_t ws_size,
                              hipStream_t stream) {
  const float* X    = (const float*)d_in[0];
  const float* Wq   = (const float*)d_in[1];
  const float* bq   = (const float*)d_in[2];
  const float* Wk   = (const float*)d_in[3];
  const float* bk   = (const float*)d_in[4];
  const float* Wv   = (const float*)d_in[5];
  const float* bv   = (const float*)d_in[6];
  const float* Wd   = (const float*)d_in[7];
  const float* bd   = (const float*)d_in[8];
  const float* gam  = (const float*)d_in[9];
  const float* bet  = (const float*)d_in[10];
  const float* delt = (const float*)d_in[11];
  const float* beul = (const float*)d_in[12];
  const float* lsc  = (const float*)d_in[13];
  float* out = (float*)d_out;

  char* w = (char*)d_ws;
  const size_t MB = 1024ull * 1024ull;
  bf16_t* Xb  = (bf16_t*)(w + 0 * MB);    // 8MB
  bf16_t* Wvb = (bf16_t*)(w + 8 * MB);    // 2MB
  bf16_t* Wdb = (bf16_t*)(w + 10 * MB);   // 2MB
  bf16_t* WqT = (bf16_t*)(w + 12 * MB);   // 2MB
  bf16_t* WkT = (bf16_t*)(w + 14 * MB);   // 2MB
  bf16_t* Pq  = (bf16_t*)(w + 16 * MB);   // 4MB
  bf16_t* Pk  = (bf16_t*)(w + 20 * MB);   // 4MB
  bf16_t* Wp  = (bf16_t*)(w + 24 * MB);   // 8MB: W'q[2], W'k[2]
  bf16_t* vb  = (bf16_t*)(w + 32 * MB);   // 8MB  (dead after transpose)
  bf16_t* qs  = (bf16_t*)(w + 40 * MB);   // 8MB
  bf16_t* ks  = (bf16_t*)(w + 48 * MB);   // 8MB
  bf16_t* vbT = (bf16_t*)(w + 56 * MB);   // 8MB
  bf16_t* ctx = (bf16_t*)(w + 64 * MB);   // 8MB
  bf16_t* hid = (bf16_t*)(w + 24 * MB);   // 8MB bf16, overlays Wp (dead after attn)
  float*  xmean  = (float*)(w + 72 * MB);             // 8KB
  float*  scores = (float*)(w + 72 * MB + 16384);     // 16KB
  float*  bsum   = (float*)(w + 72 * MB + 32768);     // 16KB
  float*  bias4  = (float*)(w + 72 * MB + 49152);     // 16KB

  const size_t WSZ = (size_t)DD * DD;

  // 0) merged casts + xmean zero + Wq/Wk transpose (one launch)
  prep_cast<<<dim3(6657), 256, 0, stream>>>(X, Wv, Wd, Wq, Wk,
                                            Xb, Wvb, Wdb, WqT, WkT, xmean);

  // 1) scores via linearity (exact fp32)
  xmean_kernel<<<dim3(4, 32, 2), 256, 0, stream>>>(X, xmean);
  scores_gemm<<<dim3(1024), 256, 0, stream>>>(xmean, Wq, bq, Wk, bk, scores);

  // 2) neural sort P (+ folded bias')
  bsum_kernel<<<dim3(4, 4), 256, 0, stream>>>(scores, bsum);
  p_kernel<<<dim3(1024, 4), 256, 0, stream>>>(scores, bsum, bq, bk, Pq, Pk, bias4);

  // 3) W' = P · W  (gemm64x64: 1024 blocks, 4/CU)
  GemmArgs gw = {};
  gw.gb[0] = {Pq,       WqT, nullptr, nullptr, Wp};
  gw.gb[1] = {Pq + WSZ, WqT, nullptr, nullptr, Wp + WSZ};
  gw.gb[2] = {Pk,       WkT, nullptr, nullptr, Wp + 2 * WSZ};
  gw.gb[3] = {Pk + WSZ, WkT, nullptr, nullptr, Wp + 3 * WSZ};
  gemm64x64<<<dim3(16, 16, 4), 256, 0, stream>>>(gw, DD, DD, DD);

  // 4) qs/ks/vb (gemm128, 768 blocks, 3/CU)
  const size_t XHALF = (size_t)LL * DD;
  GemmArgs gs = {};
  gs.gb[0] = {Xb,         Wp,           bias4,        nullptr, qs};
  gs.gb[1] = {Xb + XHALF, Wp + WSZ,     bias4 + 1024, nullptr, qs + XHALF};
  gs.gb[2] = {Xb,         Wp + 2 * WSZ, bias4 + 2048, nullptr, ks};
  gs.gb[3] = {Xb + XHALF, Wp + 3 * WSZ, bias4 + 3072, nullptr, ks + XHALF};
  gs.gb[4] = {Xb,         Wvb,          bv,           nullptr, vb};
  gs.gb[5] = {Xb + XHALF, Wvb,          bv,           nullptr, vb + XHALF};
  gemm128<<<dim3(8, 16, 6), 256, 0, stream>>>(gs, LL, DD, DD);

  // 5) euler (q pre-scaled) + V transpose (key-permuted), merged
  euler_transv<<<dim3(17408), 256, 0, stream>>>(qs, ks, delt, beul, lsc, vb, vbT);

  // 6) attention v11 (512 blocks x 256 thr, cross-tile PV pipeline)
  attn_kernel<<<dim3(512), 256, 0, stream>>>(qs, ks, vbT, ctx);

  // 7) output projection (gemm64x64: 1024 blocks)
  GemmArgs g4 = {};
  g4.gb[0] = {ctx, Wdb, bd, nullptr, hid};
  gemm64x64<<<dim3(16, 64, 1), 256, 0, stream>>>(g4, BB * LL, DD, DD);

  // 8) layernorm + residual -> fp32
  ln_kernel<<<dim3(BB * LL), 256, 0, stream>>>(hid, X, gam, bet, out);
}

// Round 11
// 277.180 us; speedup vs baseline: 1.0574x; 1.0574x over previous
//
#include <hip/hip_runtime.h>

// ---------------------------------------------------------------------------
// Euler Attention forward, MI355X gfx950 — ROUND 27.
// r26/v11 FAILED (attn 64us): persistent ping-pong regs (152 VGPR) + STAGE
// pushed behind barrier skew. REVERT to r24 per-tile body. NEW: two tiles
// per barrier interval — STAGE pairs (vmcnt(8)), one barrier pair per 2
// tiles; tile B's ds_reads overlap tile A's QK/exp2/PV inside the interval
// (transient liveness, no persistent ping-pong). Barriers 64->32. LDS 64KB
// (2 blocks/CU, grid-limited regardless). GEMMs + merged prep unchanged.
// ---------------------------------------------------------------------------

typedef unsigned short bf16_t;
typedef short frag_ab __attribute__((ext_vector_type(8)));   // 8 bf16 = 4 VGPRs
typedef float frag_cd __attribute__((ext_vector_type(4)));   // 4 fp32 acc
typedef float f32x16 __attribute__((ext_vector_type(16)));   // 32x32 acc

#define BB 2
#define LL 2048
#define DD 1024
#define HH 16
#define DH 64

#define QSCALE 0.18033688f     // 0.125 * log2(e)
#define EOFF  -17.3123404907f  // -12 * log2(e)

__device__ __forceinline__ float b2f(bf16_t u) {
  union { unsigned int i; float f; } c; c.i = ((unsigned int)u) << 16; return c.f;
}
__device__ __forceinline__ bf16_t f2b(float f) {
  union { float f; unsigned int i; } c; c.f = f;
  unsigned int r = c.i + 0x7fffu + ((c.i >> 16) & 1u);
  return (bf16_t)(r >> 16);
}
__device__ __forceinline__ unsigned int fbits(float f) {
  union { float f; unsigned int i; } c; c.f = f; return c.i;
}
__device__ __forceinline__ float waveMax(float v) {
#pragma unroll
  for (int m = 32; m > 0; m >>= 1) v = fmaxf(v, __shfl_xor(v, m));
  return v;
}
__device__ __forceinline__ float waveSum(float v) {
#pragma unroll
  for (int m = 32; m > 0; m >>= 1) v += __shfl_xor(v, m);
  return v;
}

// async global->LDS, 16B/lane; lds base wave-uniform (HW adds lane*16)
__device__ __forceinline__ void gll16(const bf16_t* g, bf16_t* l) {
  __builtin_amdgcn_global_load_lds(
      (const __attribute__((address_space(1))) void*)g,
      (__attribute__((address_space(3))) void*)l, 16, 0, 0);
}

// conflict-free tile read: [32 super-rows of 256B][16 slots of 16B]
// (row, chunk) at super=row>>1, slot=(((row&1)<<3)+chunk)^((row>>1)&15)
__device__ __forceinline__ frag_ab ld_cf(const bf16_t* base, int row, int chunk) {
  const int sup = row >> 1;
  const int t = (((row & 1) << 3) | chunk) ^ (sup & 15);
  return *(const frag_ab*)((const char*)base + sup * 256 + t * 16);
}

// pack 8 fp32 -> 8 bf16 (truncating) into an A-frag
__device__ __forceinline__ frag_ab pack8(const float* p) {
  union { unsigned int u[4]; frag_ab f; } x;
  x.u[0] = __builtin_amdgcn_perm(fbits(p[1]), fbits(p[0]), 0x07060302u);
  x.u[1] = __builtin_amdgcn_perm(fbits(p[3]), fbits(p[2]), 0x07060302u);
  x.u[2] = __builtin_amdgcn_perm(fbits(p[5]), fbits(p[4]), 0x07060302u);
  x.u[3] = __builtin_amdgcn_perm(fbits(p[7]), fbits(p[6]), 0x07060302u);
  return x.f;
}

// merged prep: X cast (blocks 0..4095), Wv cast (4096..5119),
// Wd cast (5120..6143), xmean zero (6144), Wq/Wk cast+transpose (6145..6656)
__global__ __launch_bounds__(256) void prep_cast(const float* __restrict__ X,
                                                 const float* __restrict__ Wv,
                                                 const float* __restrict__ Wd,
                                                 const float* __restrict__ Wq,
                                                 const float* __restrict__ Wk,
                                                 bf16_t* __restrict__ Xb,
                                                 bf16_t* __restrict__ Wvb,
                                                 bf16_t* __restrict__ Wdb,
                                                 bf16_t* __restrict__ WqT,
                                                 bf16_t* __restrict__ WkT,
                                                 float* __restrict__ xmean) {
  const int bid = blockIdx.x;
  const int tid = threadIdx.x;
  __shared__ bf16_t T[64][72];
  if (bid >= 6145) {                    // cast+transpose Wq/Wk, 64x64 tiles
    const int t = bid - 6145;           // 0..511: (16, 16, 2)
    const float* W = (t >> 8) ? Wk : Wq;
    bf16_t* WT = (t >> 8) ? WkT : WqT;
    const int i0 = (t & 15) * 64, m0 = ((t >> 4) & 15) * 64;
#pragma unroll
    for (int it = 0; it < 4; ++it) {
      const int idx = tid + it * 256;
      const int r = idx >> 4, c4 = (idx & 15) * 4;
      float4 v = *(const float4*)&W[(size_t)(i0 + r) * DD + m0 + c4];
      T[c4 + 0][r] = f2b(v.x);
      T[c4 + 1][r] = f2b(v.y);
      T[c4 + 2][r] = f2b(v.z);
      T[c4 + 3][r] = f2b(v.w);
    }
    __syncthreads();
#pragma unroll
    for (int it = 0; it < 2; ++it) {
      const int idx = tid + it * 256;
      const int r = idx >> 3, seg = idx & 7;
      *(uint4*)&WT[(size_t)(m0 + r) * DD + i0 + seg * 8] = *(const uint4*)&T[r][seg * 8];
    }
    return;
  }
  if (bid == 6144) {
    for (int i = tid; i < BB * DD; i += 256) xmean[i] = 0.f;
    return;
  }
  const float* in;
  bf16_t* out;
  int i;
  if (bid < 4096)      { in = X;  out = Xb;  i = bid * 256 + tid; }
  else if (bid < 5120) { in = Wv; out = Wvb; i = (bid - 4096) * 256 + tid; }
  else                 { in = Wd; out = Wdb; i = (bid - 5120) * 256 + tid; }
  float4 v = ((const float4*)in)[i];
  ushort4 o;
  o.x = f2b(v.x); o.y = f2b(v.y); o.z = f2b(v.z); o.w = f2b(v.w);
  ((ushort4*)out)[i] = o;
}

// ---------------------------------------------------------------------------
struct GemmB { const bf16_t* A; const bf16_t* Bm; const float* bias; float* Cf; bf16_t* Cb; };
struct GemmArgs { GemmB gb[6]; };

// 128x128 tile MFMA GEMM (4 waves 2x2, each 64x64) — dbuf + counted vmcnt
__global__ __launch_bounds__(256) void gemm128(GemmArgs ga, int M, int N, int K) {
  const GemmB g = ga.gb[blockIdx.z];
  const int bm = blockIdx.y * 128, bn = blockIdx.x * 128;
  __shared__ bf16_t As[2][128][32];
  __shared__ bf16_t Bs[2][128][32];
  const int tid = threadIdx.x;
  const int lane = tid & 63, w = tid >> 6;
  const int quad = lane >> 4, l16 = lane & 15;
  const int wm = (w >> 1) * 64, wn = (w & 1) * 64;
  const int wbase = w << 9;

  frag_cd acc[4][4];
#pragma unroll
  for (int i = 0; i < 4; ++i)
#pragma unroll
    for (int j = 0; j < 4; ++j)
#pragma unroll
      for (int r = 0; r < 4; ++r) acc[i][j][r] = 0.f;

  const int r0 = tid >> 2, s0 = (tid & 3) * 8;
  const int r1 = (tid + 256) >> 2, s1 = ((tid + 256) & 3) * 8;
  const size_t aoff0 = (size_t)(bm + r0) * K + s0;
  const size_t aoff1 = (size_t)(bm + r1) * K + s1;
  const size_t boff0 = (size_t)(bn + r0) * K + s0;
  const size_t boff1 = (size_t)(bn + r1) * K + s1;

  auto STAGE = [&](int buf, int k0) {
    bf16_t* Af = &As[buf][0][0];
    bf16_t* Bf = &Bs[buf][0][0];
    gll16(g.A + aoff0 + k0, Af + wbase);
    gll16(g.A + aoff1 + k0, Af + 2048 + wbase);
    gll16(g.Bm + boff0 + k0, Bf + wbase);
    gll16(g.Bm + boff1 + k0, Bf + 2048 + wbase);
  };

  STAGE(0, 0);
  int cur = 0;
  for (int k0 = 0; k0 < K; k0 += 32) {
    if (k0 + 32 < K) {
      STAGE(cur ^ 1, k0 + 32);                      // 4 next-tile loads in flight
      asm volatile("s_waitcnt vmcnt(4)" ::: "memory");  // cur tile landed
    } else {
      asm volatile("s_waitcnt vmcnt(0)" ::: "memory");
    }
    __builtin_amdgcn_s_barrier();
    frag_ab af[4], bfr[4];
#pragma unroll
    for (int i = 0; i < 4; ++i) {
      af[i]  = *(const frag_ab*)&As[cur][wm + i * 16 + l16][quad * 8];
      bfr[i] = *(const frag_ab*)&Bs[cur][wn + i * 16 + l16][quad * 8];
    }
#pragma unroll
    for (int i = 0; i < 4; ++i)
#pragma unroll
      for (int j = 0; j < 4; ++j)
        acc[i][j] = __builtin_amdgcn_mfma_f32_16x16x32_bf16(af[i], bfr[j], acc[i][j], 0, 0, 0);
    __builtin_amdgcn_s_barrier();
    cur ^= 1;
  }

#pragma unroll
  for (int i = 0; i < 4; ++i) {
#pragma unroll
    for (int r = 0; r < 4; ++r) {
      const int row = bm + wm + i * 16 + quad * 4 + r;
#pragma unroll
      for (int j = 0; j < 4; ++j) {
        const int col = bn + wn + j * 16 + l16;
        float v = acc[i][j][r];
        if (g.bias) v += g.bias[col];
        if (g.Cf) g.Cf[(size_t)row * N + col] = v;
        if (g.Cb) g.Cb[(size_t)row * N + col] = f2b(v);
      }
    }
  }
}

// 64x64 tile MFMA GEMM (4 waves 2x2, each 32x32) — dbuf + counted vmcnt
__global__ __launch_bounds__(256) void gemm64x64(GemmArgs ga, int M, int N, int K) {
  const GemmB g = ga.gb[blockIdx.z];
  const int bm = blockIdx.y * 64, bn = blockIdx.x * 64;
  __shared__ bf16_t As[2][64][32];
  __shared__ bf16_t Bs[2][64][32];
  const int tid = threadIdx.x;
  const int lane = tid & 63, w = tid >> 6;
  const int quad = lane >> 4, l16 = lane & 15;
  const int wm = (w >> 1) * 32, wn = (w & 1) * 32;
  const int wbase = w << 9;

  frag_cd acc[2][2];
#pragma unroll
  for (int i = 0; i < 2; ++i)
#pragma unroll
    for (int j = 0; j < 2; ++j)
#pragma unroll
      for (int r = 0; r < 4; ++r) acc[i][j][r] = 0.f;

  const int r0 = tid >> 2, s0 = (tid & 3) * 8;
  const size_t aoff0 = (size_t)(bm + r0) * K + s0;
  const size_t boff0 = (size_t)(bn + r0) * K + s0;

  auto STAGE = [&](int buf, int k0) {
    gll16(g.A + aoff0 + k0, &As[buf][0][0] + wbase);
    gll16(g.Bm + boff0 + k0, &Bs[buf][0][0] + wbase);
  };

  STAGE(0, 0);
  int cur = 0;
  for (int k0 = 0; k0 < K; k0 += 32) {
    if (k0 + 32 < K) {
      STAGE(cur ^ 1, k0 + 32);                      // 2 next-tile loads in flight
      asm volatile("s_waitcnt vmcnt(2)" ::: "memory");  // cur tile landed
    } else {
      asm volatile("s_waitcnt vmcnt(0)" ::: "memory");
    }
    __builtin_amdgcn_s_barrier();
    frag_ab af[2], bfr[2];
#pragma unroll
    for (int i = 0; i < 2; ++i) {
      af[i]  = *(const frag_ab*)&As[cur][wm + i * 16 + l16][quad * 8];
      bfr[i] = *(const frag_ab*)&Bs[cur][wn + i * 16 + l16][quad * 8];
    }
#pragma unroll
    for (int i = 0; i < 2; ++i)
#pragma unroll
      for (int j = 0; j < 2; ++j)
        acc[i][j] = __builtin_amdgcn_mfma_f32_16x16x32_bf16(af[i], bfr[j], acc[i][j], 0, 0, 0);
    __builtin_amdgcn_s_barrier();
    cur ^= 1;
  }

#pragma unroll
  for (int i = 0; i < 2; ++i) {
#pragma unroll
    for (int r = 0; r < 4; ++r) {
      const int row = bm + wm + i * 16 + quad * 4 + r;
#pragma unroll
      for (int j = 0; j < 2; ++j) {
        const int col = bn + wn + j * 16 + l16;
        float v = acc[i][j][r];
        if (g.bias) v += g.bias[col];
        if (g.Cf) g.Cf[(size_t)row * N + col] = v;
        if (g.Cb) g.Cb[(size_t)row * N + col] = f2b(v);
      }
    }
  }
}

// xmean[b][d] = mean over L of X[b][l][d]
__global__ __launch_bounds__(256) void xmean_kernel(const float* __restrict__ X,
                                                    float* __restrict__ xmean) {
  const int d = blockIdx.x * 256 + threadIdx.x;
  const int b = blockIdx.z;
  const int l0 = blockIdx.y * 64;
  float s = 0.f;
  for (int l = l0; l < l0 + 64; ++l)
    s += X[((size_t)b * LL + l) * DD + d];
  atomicAdd(&xmean[b * DD + d], s * (1.f / (float)LL));
}

// scores: one wave per output
__global__ __launch_bounds__(256) void scores_gemm(const float* __restrict__ xmean,
                                                   const float* __restrict__ Wq,
                                                   const float* __restrict__ bq,
                                                   const float* __restrict__ Wk,
                                                   const float* __restrict__ bk,
                                                   float* __restrict__ scores) {
  const int w = threadIdx.x >> 6, lane = threadIdx.x & 63;
  const int idx = blockIdx.x * 4 + w;
  const int t = idx >> 11, b = (idx >> 10) & 1, i = idx & 1023;
  const float* W = t ? Wk : Wq;
  const float* bias = t ? bk : bq;
  const float* xm = xmean + b * DD;
  float sum = 0.f;
#pragma unroll
  for (int k = 0; k < 4; ++k) {
    float4 wv = *(const float4*)&W[(size_t)i * DD + k * 256 + lane * 4];
    float4 xv = *(const float4*)&xm[k * 256 + lane * 4];
    sum += wv.x * xv.x + wv.y * xv.y + wv.z * xv.z + wv.w * xv.w;
  }
  sum = waveSum(sum);
  if (lane == 0) scores[idx] = sum + bias[i];
}

// Bsum: 16 blocks, float4 LDS reads
__global__ __launch_bounds__(256) void bsum_kernel(const float* __restrict__ scores,
                                                   float* __restrict__ bsum) {
  __shared__ float sc[DD];
  const int z = blockIdx.x, jb = blockIdx.y, tid = threadIdx.x;
#pragma unroll
  for (int s = 0; s < 4; ++s) sc[tid + s * 256] = scores[z * DD + tid + s * 256];
  __syncthreads();
  const int j = jb * 256 + tid;
  const float si = sc[j];
  float s = 0.f;
  for (int m = 0; m < DD; m += 4) {
    float4 v = *(const float4*)&sc[m];
    s += fabsf(si - v.x) + fabsf(si - v.y) + fabsf(si - v.z) + fabsf(si - v.w);
  }
  bsum[z * DD + j] = s;
}

// P row + folded bias'
__global__ __launch_bounds__(256) void p_kernel(const float* __restrict__ scores,
                                                const float* __restrict__ bsum,
                                                const float* __restrict__ bq,
                                                const float* __restrict__ bk,
                                                bf16_t* __restrict__ Pq,
                                                bf16_t* __restrict__ Pk,
                                                float* __restrict__ bias4) {
  const int i = blockIdx.x;
  const int z = blockIdx.y;
  const int t = z >> 1, b = z & 1;
  const float* sc = scores + z * DD;
  const float* bs = bsum + z * DD;
  const float* bias = t ? bk : bq;
  const float scal = 1023.f - 2.f * (float)i;
  const int tid = threadIdx.x;
  __shared__ float redA[4], redB[4], redC[4];

  float lg[4], bb[4];
  float mx = -1e30f;
#pragma unroll
  for (int s = 0; s < 4; ++s) {
    const int j = tid + s * 256;
    lg[s] = sc[j] * scal - bs[j];
    bb[s] = bias[j];
    mx = fmaxf(mx, lg[s]);
  }
  mx = waveMax(mx);
  if ((tid & 63) == 0) redA[tid >> 6] = mx;
  __syncthreads();
  const float M = fmaxf(fmaxf(redA[0], redA[1]), fmaxf(redA[2], redA[3]));
  float sum = 0.f, dot = 0.f;
#pragma unroll
  for (int s = 0; s < 4; ++s) {
    lg[s] = __expf(lg[s] - M);
    sum += lg[s];
    dot += lg[s] * bb[s];
  }
  sum = waveSum(sum); dot = waveSum(dot);
  if ((tid & 63) == 0) { redB[tid >> 6] = sum; redC[tid >> 6] = dot; }
  __syncthreads();
  const float inv = 1.f / (redB[0] + redB[1] + redB[2] + redB[3]);
  bf16_t* P = (t ? Pk : Pq) + ((size_t)b << 20) + (size_t)i * DD;
#pragma unroll
  for (int s = 0; s < 4; ++s) P[tid + s * 256] = f2b(lg[s] * inv);
  if (tid == 0)
    bias4[t * 2048 + b * 1024 + i] = (redC[0] + redC[1] + redC[2] + redC[3]) * inv;
}

// merged euler (blocks 0..16383, q scaled by QSCALE) + V transpose (16384..)
// V transpose applies the 32x32x16 k-slot permutation: within each 16-key
// block of L, output position order is [0-3, 8-11, 4-7, 12-15] (bit2<->bit3
// involution), so attn's PV B-frags read contiguous b128.
__global__ __launch_bounds__(256) void euler_transv(bf16_t* __restrict__ qs,
                                                    bf16_t* __restrict__ ks,
                                                    const float* __restrict__ delta,
                                                    const float* __restrict__ beul,
                                                    const float* __restrict__ lsc,
                                                    const bf16_t* __restrict__ vb,
                                                    bf16_t* __restrict__ vbT) {
  __shared__ bf16_t T[64][72];
  const int bid = blockIdx.x;
  const int tid = threadIdx.x;
  if (bid < 16384) {
    const int isq = (bid < 8192);
    unsigned int* buf = (unsigned int*)(isq ? qs : ks);
    const int idx = (isq ? bid : bid - 8192) * 256 + tid;
    const int c = idx & 511;
    const size_t n = idx >> 9;
    const unsigned int u = buf[n * 512 + c];
    const float r = b2f((bf16_t)(u & 0xffffu));
    const float p = b2f((bf16_t)(u >> 16));
    float lam = sqrtf(r * r + p * p + 1e-6f);
    float th = atan2f(p, r) * delta[c];
    if (isq) th += beul[c];
    lam *= __expf(fminf(fmaxf(lsc[c], -5.f), 5.f));
    if (isq) lam *= QSCALE;    // fold attention scale into q (q only feeds attn)
    float sn, cs;
    __sincosf(th, &sn, &cs);
    buf[n * 512 + c] = ((unsigned int)f2b(lam * sn) << 16) | (unsigned int)f2b(lam * cs);
    return;
  }
  const int tb = bid - 16384;                 // 0..1023: (32, 16, 2)
  const int l0 = (tb & 31) * 64, d0 = ((tb >> 5) & 15) * 64, b = tb >> 9;
  for (int i = tid; i < 512; i += 256) {
    const int r = i >> 3, seg = i & 7;
    uint4 v = *(const uint4*)&vb[((size_t)b * LL + l0 + r) * DD + d0 + seg * 8];
    const bf16_t* vs = (const bf16_t*)&v;
#pragma unroll
    for (int j = 0; j < 8; ++j) T[seg * 8 + j][r] = vs[j];
  }
  __syncthreads();
  for (int i = tid; i < 512; i += 256) {
    const int r = i >> 3, seg = i & 7;
    // permuted gather: positions seg*8..+8 hold keys {base..base+3, base+8..+11}
    const int kb = (seg >> 1) * 16 + (seg & 1) * 4;
    uint2 lo = *(const uint2*)&T[r][kb];
    uint2 hi2 = *(const uint2*)&T[r][kb + 8];
    uint4 o; o.x = lo.x; o.y = lo.y; o.z = hi2.x; o.w = hi2.y;
    *(uint4*)&vbT[((size_t)b * DD + d0 + r) * LL + l0 + seg * 8] = o;
  }
}

// ---------------------------------------------------------------------------
// Flash attention v12: 512 blocks x 256 thr, 4 waves x 32 queries (32x32x16).
// r24 per-tile body (P in regs, key-permuted V, conflict-free LDS layout);
// TWO tiles per barrier interval: STAGE2 pairs + vmcnt(8); no barrier
// between the pair's computes -> tile B's ds_reads overlap tile A's
// QK/exp2/PV (transient liveness, no persistent ping-pong regs).
// ---------------------------------------------------------------------------
__global__ __launch_bounds__(256) void attn_kernel(const bf16_t* __restrict__ Q,
                                                   const bf16_t* __restrict__ Kt,
                                                   const bf16_t* __restrict__ VT,
                                                   bf16_t* __restrict__ O) {
  const int bid = blockIdx.x;
  const int swz = (bid & 7) * 64 + (bid >> 3);    // bijective, 64 blocks/XCD
  const int g = swz >> 4;                         // 4 bh-groups per XCD
  const int qt = swz & 15;
  const int b = g >> 4, h = g & 15;
  const int q0 = qt * 128;
  const int tid = threadIdx.x, w = tid >> 6, lane = tid & 63;
  const int hi = lane >> 5, l31 = lane & 31;

  __shared__ bf16_t Ks[2][2][64 * 64];   // [buf][pair-slot]
  __shared__ bf16_t Vs[2][2][64 * 64];

  const size_t base = (size_t)b * LL * DD + (size_t)h * DH;
  const size_t vtb = (size_t)(b * DD + h * DH) * LL;

  // Q fragments straight to registers (q pre-scaled by QSCALE at euler)
  frag_ab bq[4];
#pragma unroll
  for (int kd = 0; kd < 4; ++kd)
    bq[kd] = *(const frag_ab*)
        &Q[base + (size_t)(q0 + w * 32 + l31) * DD + kd * 16 + hi * 8];

  // constant ones-column B-frag: col 0 => lanes with l31==0 hold 8x 1.0
  frag_ab bone;
  {
    const short o = (l31 == 0) ? (short)0x3F80 : (short)0;
#pragma unroll
    for (int j = 0; j < 8; ++j) bone[j] = o;
  }

  f32x16 o_[2], l5;
#pragma unroll
  for (int i = 0; i < 16; ++i) { o_[0][i] = 0.f; o_[1][i] = 0.f; l5[i] = 0.f; }

  // STAGE decode for conflict-free layout (r24)
  const int sup_l = lane >> 4;
  const int sl15 = lane & 15;

  auto STAGE2 = [&](int buf, int kt) {    // stages tiles kt and kt+1
#pragma unroll
    for (int u = 0; u < 2; ++u) {
#pragma unroll
      for (int t = 0; t < 2; ++t) {
        const int supb = w * 8 + t * 4;
        const int sup = supb + sup_l;
        const int tt = sl15 ^ (sup & 15);
        const int row = sup * 2 + (tt >> 3);
        const int ch = tt & 7;
        gll16(Kt + base + (size_t)((kt + u) * 64 + row) * DD + ch * 8,
              &Ks[buf][u][(w * 16 + t * 8) * 64]);
        gll16(VT + vtb + (size_t)row * LL + (kt + u) * 64 + ch * 8,
              &Vs[buf][u][(w * 16 + t * 8) * 64]);
      }
    }
  };

  STAGE2(0, 0);
  int cur = 0;
  const int NT = LL / 64;
  for (int kt = 0; kt < NT; kt += 2) {
    if (kt + 2 < NT) {
      STAGE2(cur ^ 1, kt + 2);                      // 8 next-pair loads in flight
      asm volatile("s_waitcnt vmcnt(8)" ::: "memory");  // cur pair landed
    } else {
      asm volatile("s_waitcnt vmcnt(0)" ::: "memory");
    }
    __builtin_amdgcn_s_barrier();                   // all waves staged cur pair

#pragma unroll
    for (int u = 0; u < 2; ++u) {
      const bf16_t* Kb = Ks[cur][u];
      const bf16_t* Vb = Vs[cur][u];

      // QK: S^T = K·Q^T + EOFF per 32-key half; P kept in registers.
      // D layout: col=l31 (query), row(reg r) = (r&3)+8*(r>>2)+4*hi (key)
      frag_ab pa[4];
#pragma unroll
      for (int s = 0; s < 2; ++s) {
        frag_ab ak[4];
#pragma unroll
        for (int kd = 0; kd < 4; ++kd)
          ak[kd] = ld_cf(Kb, s * 32 + l31, kd * 2 + hi);
        f32x16 z;
#pragma unroll
        for (int i = 0; i < 16; ++i) z[i] = EOFF;
#pragma unroll
        for (int kd = 0; kd < 4; ++kd)
          z = __builtin_amdgcn_mfma_f32_32x32x16_bf16(ak[kd], bq[kd], z, 0, 0, 0);
#pragma unroll
        for (int t = 0; t < 2; ++t) {
          float p[8];
#pragma unroll
          for (int j = 0; j < 8; ++j) p[j] = __builtin_amdgcn_exp2f(z[t * 8 + j]);
          pa[s * 2 + t] = pack8(p);   // A-frag kstep 2s+t: key(hi,j) matches V perm
        }
      }

      // l += P · ones (A-frags reused; MFMA pipe)
#pragma unroll
      for (int k = 0; k < 4; ++k)
        l5 = __builtin_amdgcn_mfma_f32_32x32x16_bf16(pa[k], bone, l5, 0, 0, 0);

      // O += P V  (V key-order pre-permuted in global => contiguous B-frags)
#pragma unroll
      for (int dt = 0; dt < 2; ++dt)
#pragma unroll
        for (int k = 0; k < 4; ++k) {
          frag_ab bv = ld_cf(Vb, dt * 32 + l31, k * 2 + hi);
          o_[dt] = __builtin_amdgcn_mfma_f32_32x32x16_bf16(pa[k], bv, o_[dt], 0, 0, 0);
        }
    }

    __builtin_amdgcn_s_barrier();                   // all done reading cur pair
    cur ^= 1;
  }

  // l[q] lives at col 0 => lane hi*32, reg r (q = (r&3)+8*(r>>2)+4*hi)
  const int src = (lane >> 5) << 5;
  float lf[16];
#pragma unroll
  for (int r = 0; r < 16; ++r) lf[r] = 1.f / __shfl(l5[r], src);

#pragma unroll
  for (int dt = 0; dt < 2; ++dt)
#pragma unroll
    for (int r = 0; r < 16; ++r) {
      const int ql = (r & 3) + 8 * (r >> 2) + 4 * hi;
      O[base + (size_t)(q0 + w * 32 + ql) * DD + dt * 32 + l31] =
          f2b(o_[dt][r] * lf[r]);
    }
}

// layernorm(hidden(bf16) + X) * gamma + beta -> FP32 out
__global__ __launch_bounds__(256) void ln_kernel(const bf16_t* __restrict__ hidden,
                                                 const float* __restrict__ x0,
                                                 const float* __restrict__ gamma,
                                                 const float* __restrict__ beta,
                                                 float* __restrict__ out) {
  const int row = blockIdx.x;
  const int tid = threadIdx.x;
  __shared__ float red1[4], red2[4];
  float v[4];
  float s1 = 0.f, s2 = 0.f;
#pragma unroll
  for (int s = 0; s < 4; ++s) {
    const int c = tid + s * 256;
    const float x = b2f(hidden[(size_t)row * DD + c]) + x0[(size_t)row * DD + c];
    v[s] = x; s1 += x; s2 += x * x;
  }
  s1 = waveSum(s1); s2 = waveSum(s2);
  if ((tid & 63) == 0) { red1[tid >> 6] = s1; red2[tid >> 6] = s2; }
  __syncthreads();
  const float t1 = red1[0] + red1[1] + red1[2] + red1[3];
  const float t2 = red2[0] + red2[1] + red2[2] + red2[3];
  const float mu = t1 * (1.f / DD);
  const float var = t2 * (1.f / DD) - mu * mu;
  const float inv = rsqrtf(var + 1e-12f);
#pragma unroll
  for (int s = 0; s < 4; ++s) {
    const int c = tid + s * 256;
    out[(size_t)row * DD + c] = (v[s] - mu) * inv * gamma[c] + beta[c];
  }
}

// ---------------------------------------------------------------------------
extern "C" void kernel_launch(void* const* d_in, const int* in_sizes, int n_in,
                              void* d_out, int out_size, void* d_ws, size_t ws_size,
                              hipStream_t stream) {
  const float* X    = (const float*)d_in[0];
  const float* Wq   = (const float*)d_in[1];
  const float* bq   = (const float*)d_in[2];
  const float* Wk   = (const float*)d_in[3];
  const float* bk   = (const float*)d_in[4];
  const float* Wv   = (const float*)d_in[5];
  const float* bv   = (const float*)d_in[6];
  const float* Wd   = (const float*)d_in[7];
  const float* bd   = (const float*)d_in[8];
  const float* gam  = (const float*)d_in[9];
  const float* bet  = (const float*)d_in[10];
  const float* delt = (const float*)d_in[11];
  const float* beul = (const float*)d_in[12];
  const float* lsc  = (const float*)d_in[13];
  float* out = (float*)d_out;

  char* w = (char*)d_ws;
  const size_t MB = 1024ull * 1024ull;
  bf16_t* Xb  = (bf16_t*)(w + 0 * MB);    // 8MB
  bf16_t* Wvb = (bf16_t*)(w + 8 * MB);    // 2MB
  bf16_t* Wdb = (bf16_t*)(w + 10 * MB);   // 2MB
  bf16_t* WqT = (bf16_t*)(w + 12 * MB);   // 2MB
  bf16_t* WkT = (bf16_t*)(w + 14 * MB);   // 2MB
  bf16_t* Pq  = (bf16_t*)(w + 16 * MB);   // 4MB
  bf16_t* Pk  = (bf16_t*)(w + 20 * MB);   // 4MB
  bf16_t* Wp  = (bf16_t*)(w + 24 * MB);   // 8MB: W'q[2], W'k[2]
  bf16_t* vb  = (bf16_t*)(w + 32 * MB);   // 8MB  (dead after transpose)
  bf16_t* qs  = (bf16_t*)(w + 40 * MB);   // 8MB
  bf16_t* ks  = (bf16_t*)(w + 48 * MB);   // 8MB
  bf16_t* vbT = (bf16_t*)(w + 56 * MB);   // 8MB
  bf16_t* ctx = (bf16_t*)(w + 64 * MB);   // 8MB
  bf16_t* hid = (bf16_t*)(w + 24 * MB);   // 8MB bf16, overlays Wp (dead after attn)
  float*  xmean  = (float*)(w + 72 * MB);             // 8KB
  float*  scores = (float*)(w + 72 * MB + 16384);     // 16KB
  float*  bsum   = (float*)(w + 72 * MB + 32768);     // 16KB
  float*  bias4  = (float*)(w + 72 * MB + 49152);     // 16KB

  const size_t WSZ = (size_t)DD * DD;

  // 0) merged casts + xmean zero + Wq/Wk transpose (one launch)
  prep_cast<<<dim3(6657), 256, 0, stream>>>(X, Wv, Wd, Wq, Wk,
                                            Xb, Wvb, Wdb, WqT, WkT, xmean);

  // 1) scores via linearity (exact fp32)
  xmean_kernel<<<dim3(4, 32, 2), 256, 0, stream>>>(X, xmean);
  scores_gemm<<<dim3(1024), 256, 0, stream>>>(xmean, Wq, bq, Wk, bk, scores);

  // 2) neural sort P (+ folded bias')
  bsum_kernel<<<dim3(4, 4), 256, 0, stream>>>(scores, bsum);
  p_kernel<<<dim3(1024, 4), 256, 0, stream>>>(scores, bsum, bq, bk, Pq, Pk, bias4);

  // 3) W' = P · W  (gemm64x64: 1024 blocks, 4/CU)
  GemmArgs gw = {};
  gw.gb[0] = {Pq,       WqT, nullptr, nullptr, Wp};
  gw.gb[1] = {Pq + WSZ, WqT, nullptr, nullptr, Wp + WSZ};
  gw.gb[2] = {Pk,       WkT, nullptr, nullptr, Wp + 2 * WSZ};
  gw.gb[3] = {Pk + WSZ, WkT, nullptr, nullptr, Wp + 3 * WSZ};
  gemm64x64<<<dim3(16, 16, 4), 256, 0, stream>>>(gw, DD, DD, DD);

  // 4) qs/ks/vb (gemm128, 768 blocks, 3/CU)
  const size_t XHALF = (size_t)LL * DD;
  GemmArgs gs = {};
  gs.gb[0] = {Xb,         Wp,           bias4,        nullptr, qs};
  gs.gb[1] = {Xb + XHALF, Wp + WSZ,     bias4 + 1024, nullptr, qs + XHALF};
  gs.gb[2] = {Xb,         Wp + 2 * WSZ, bias4 + 2048, nullptr, ks};
  gs.gb[3] = {Xb + XHALF, Wp + 3 * WSZ, bias4 + 3072, nullptr, ks + XHALF};
  gs.gb[4] = {Xb,         Wvb,          bv,           nullptr, vb};
  gs.gb[5] = {Xb + XHALF, Wvb,          bv,           nullptr, vb + XHALF};
  gemm128<<<dim3(8, 16, 6), 256, 0, stream>>>(gs, LL, DD, DD);

  // 5) euler (q pre-scaled) + V transpose (key-permuted), merged
  euler_transv<<<dim3(17408), 256, 0, stream>>>(qs, ks, delt, beul, lsc, vb, vbT);

  // 6) attention v12 (512 blocks x 256 thr, 2 tiles per barrier interval)
  attn_kernel<<<dim3(512), 256, 0, stream>>>(qs, ks, vbT, ctx);

  // 7) output projection (gemm64x64: 1024 blocks)
  GemmArgs g4 = {};
  g4.gb[0] = {ctx, Wdb, bd, nullptr, hid};
  gemm64x64<<<dim3(16, 64, 1), 256, 0, stream>>>(g4, BB * LL, DD, DD);

  // 8) layernorm + residual -> fp32
  ln_kernel<<<dim3(BB * LL), 256, 0, stream>>>(hid, X, gam, bet, out);
}

// Round 13
// 275.565 us; speedup vs baseline: 1.0636x; 1.0059x over previous
//
#include <hip/hip_runtime.h>

// ---------------------------------------------------------------------------
// Euler Attention forward, MI355X gfx950 — ROUND 29 (r28 resubmit).
// r28 bench: infra failure #3 ("container failed twice"; r22/r25 precedent:
// unmodified resubmits ran). Kernel re-audit: gemm cf-layout write/read
// involution exact, 2-way-max banks (free), sync structure byte-identical to
// proven r20/r24 pattern, swizzle bijective. Resubmitting unchanged:
//  - gemm128+gemm64x64: conflict-free LDS layout (supers of 4 rows/256B,
//    slot=(((row&3)<<2)|seg)^(sup&15)), pre-swizzled gll16 source (m173).
//  - gemm128: bijective XCD swizzle (768=8x96) for A-panel L2 reuse (T1).
//  - attn: r24 v10 verbatim (proven 49.6us).
// ---------------------------------------------------------------------------

typedef unsigned short bf16_t;
typedef short frag_ab __attribute__((ext_vector_type(8)));   // 8 bf16 = 4 VGPRs
typedef float frag_cd __attribute__((ext_vector_type(4)));   // 4 fp32 acc
typedef float f32x16 __attribute__((ext_vector_type(16)));   // 32x32 acc

#define BB 2
#define LL 2048
#define DD 1024
#define HH 16
#define DH 64

#define QSCALE 0.18033688f     // 0.125 * log2(e)
#define EOFF  -17.3123404907f  // -12 * log2(e)

__device__ __forceinline__ float b2f(bf16_t u) {
  union { unsigned int i; float f; } c; c.i = ((unsigned int)u) << 16; return c.f;
}
__device__ __forceinline__ bf16_t f2b(float f) {
  union { float f; unsigned int i; } c; c.f = f;
  unsigned int r = c.i + 0x7fffu + ((c.i >> 16) & 1u);
  return (bf16_t)(r >> 16);
}
__device__ __forceinline__ unsigned int fbits(float f) {
  union { float f; unsigned int i; } c; c.f = f; return c.i;
}
__device__ __forceinline__ float waveMax(float v) {
#pragma unroll
  for (int m = 32; m > 0; m >>= 1) v = fmaxf(v, __shfl_xor(v, m));
  return v;
}
__device__ __forceinline__ float waveSum(float v) {
#pragma unroll
  for (int m = 32; m > 0; m >>= 1) v += __shfl_xor(v, m);
  return v;
}

// async global->LDS, 16B/lane; lds base wave-uniform (HW adds lane*16)
__device__ __forceinline__ void gll16(const bf16_t* g, bf16_t* l) {
  __builtin_amdgcn_global_load_lds(
      (const __attribute__((address_space(1))) void*)g,
      (__attribute__((address_space(3))) void*)l, 16, 0, 0);
}

// conflict-free tile read, 64-row/128B-row tiles (attn K/V):
// [32 super-rows of 256B][16 slots]; (row,chunk8) at super=row>>1,
// slot=(((row&1)<<3)|chunk)^(super&15)
__device__ __forceinline__ frag_ab ld_cf(const bf16_t* base, int row, int chunk) {
  const int sup = row >> 1;
  const int t = (((row & 1) << 3) | chunk) ^ (sup & 15);
  return *(const frag_ab*)((const char*)base + sup * 256 + t * 16);
}

// conflict-free tile read, 32-col/64B-row tiles (gemm As/Bs):
// supers of 4 rows (256B); (row,seg4) at slot=(((row&3)<<2)|seg)^(sup&15)
__device__ __forceinline__ frag_ab ld_cf4(const bf16_t* base, int row, int seg4) {
  const int sup = row >> 2;
  const int t = ((((row & 3) << 2) | seg4) ^ (sup & 15));
  return *(const frag_ab*)((const char*)base + sup * 256 + t * 16);
}

// pack 8 fp32 -> 8 bf16 (truncating) into an A-frag
__device__ __forceinline__ frag_ab pack8(const float* p) {
  union { unsigned int u[4]; frag_ab f; } x;
  x.u[0] = __builtin_amdgcn_perm(fbits(p[1]), fbits(p[0]), 0x07060302u);
  x.u[1] = __builtin_amdgcn_perm(fbits(p[3]), fbits(p[2]), 0x07060302u);
  x.u[2] = __builtin_amdgcn_perm(fbits(p[5]), fbits(p[4]), 0x07060302u);
  x.u[3] = __builtin_amdgcn_perm(fbits(p[7]), fbits(p[6]), 0x07060302u);
  return x.f;
}

// merged prep: X cast (blocks 0..4095), Wv cast (4096..5119),
// Wd cast (5120..6143), xmean zero (6144), Wq/Wk cast+transpose (6145..6656)
__global__ __launch_bounds__(256) void prep_cast(const float* __restrict__ X,
                                                 const float* __restrict__ Wv,
                                                 const float* __restrict__ Wd,
                                                 const float* __restrict__ Wq,
                                                 const float* __restrict__ Wk,
                                                 bf16_t* __restrict__ Xb,
                                                 bf16_t* __restrict__ Wvb,
                                                 bf16_t* __restrict__ Wdb,
                                                 bf16_t* __restrict__ WqT,
                                                 bf16_t* __restrict__ WkT,
                                                 float* __restrict__ xmean) {
  const int bid = blockIdx.x;
  const int tid = threadIdx.x;
  __shared__ bf16_t T[64][72];
  if (bid >= 6145) {                    // cast+transpose Wq/Wk, 64x64 tiles
    const int t = bid - 6145;           // 0..511: (16, 16, 2)
    const float* W = (t >> 8) ? Wk : Wq;
    bf16_t* WT = (t >> 8) ? WkT : WqT;
    const int i0 = (t & 15) * 64, m0 = ((t >> 4) & 15) * 64;
#pragma unroll
    for (int it = 0; it < 4; ++it) {
      const int idx = tid + it * 256;
      const int r = idx >> 4, c4 = (idx & 15) * 4;
      float4 v = *(const float4*)&W[(size_t)(i0 + r) * DD + m0 + c4];
      T[c4 + 0][r] = f2b(v.x);
      T[c4 + 1][r] = f2b(v.y);
      T[c4 + 2][r] = f2b(v.z);
      T[c4 + 3][r] = f2b(v.w);
    }
    __syncthreads();
#pragma unroll
    for (int it = 0; it < 2; ++it) {
      const int idx = tid + it * 256;
      const int r = idx >> 3, seg = idx & 7;
      *(uint4*)&WT[(size_t)(m0 + r) * DD + i0 + seg * 8] = *(const uint4*)&T[r][seg * 8];
    }
    return;
  }
  if (bid == 6144) {
    for (int i = tid; i < BB * DD; i += 256) xmean[i] = 0.f;
    return;
  }
  const float* in;
  bf16_t* out;
  int i;
  if (bid < 4096)      { in = X;  out = Xb;  i = bid * 256 + tid; }
  else if (bid < 5120) { in = Wv; out = Wvb; i = (bid - 4096) * 256 + tid; }
  else                 { in = Wd; out = Wdb; i = (bid - 5120) * 256 + tid; }
  float4 v = ((const float4*)in)[i];
  ushort4 o;
  o.x = f2b(v.x); o.y = f2b(v.y); o.z = f2b(v.z); o.w = f2b(v.w);
  ((ushort4*)out)[i] = o;
}

// ---------------------------------------------------------------------------
struct GemmB { const bf16_t* A; const bf16_t* Bm; const float* bias; float* Cf; bf16_t* Cb; };
struct GemmArgs { GemmB gb[6]; };

// 128x128 tile MFMA GEMM (4 waves 2x2, each 64x64)
// dbuf + counted vmcnt + conflict-free LDS layout + XCD swizzle
__global__ __launch_bounds__(256) void gemm128(GemmArgs ga, int M, int N, int K) {
  // XCD swizzle: 768 blocks = 8 XCDs x 96; contiguous logical tiles per XCD
  const int orig = blockIdx.x + 8 * (blockIdx.y + 16 * blockIdx.z);
  const int swz = (orig & 7) * 96 + (orig >> 3);
  const int bx = swz & 7, by = (swz >> 3) & 15, bz = swz >> 7;
  const GemmB g = ga.gb[bz];
  const int bm = by * 128, bn = bx * 128;
  __shared__ bf16_t As[2][128][32];
  __shared__ bf16_t Bs[2][128][32];
  const int tid = threadIdx.x;
  const int lane = tid & 63, w = tid >> 6;
  const int quad = lane >> 4, l16 = lane & 15;
  const int wm = (w >> 1) * 64, wn = (w & 1) * 64;
  const int wbase = w << 9;

  frag_cd acc[4][4];
#pragma unroll
  for (int i = 0; i < 4; ++i)
#pragma unroll
    for (int j = 0; j < 4; ++j)
#pragma unroll
      for (int r = 0; r < 4; ++r) acc[i][j][r] = 0.f;

  // pre-swizzled global source decode: call c covers supers c*16+4w+..+3;
  // storage slot s=lane&15 of super holds (row,seg): ((row&3)<<2)|seg = s^(sup&15)
  const int sup0 = 4 * w + (lane >> 4);
  const int tt0 = (lane & 15) ^ (sup0 & 15);
  const int row0 = sup0 * 4 + (tt0 >> 2), seg0 = tt0 & 3;
  const int row1 = row0 + 64;           // call 1: sup+16, same low bits
  const size_t aoff0 = (size_t)(bm + row0) * K + seg0 * 8;
  const size_t aoff1 = (size_t)(bm + row1) * K + seg0 * 8;
  const size_t boff0 = (size_t)(bn + row0) * K + seg0 * 8;
  const size_t boff1 = (size_t)(bn + row1) * K + seg0 * 8;

  auto STAGE = [&](int buf, int k0) {
    bf16_t* Af = &As[buf][0][0];
    bf16_t* Bf = &Bs[buf][0][0];
    gll16(g.A + aoff0 + k0, Af + wbase);
    gll16(g.A + aoff1 + k0, Af + 2048 + wbase);
    gll16(g.Bm + boff0 + k0, Bf + wbase);
    gll16(g.Bm + boff1 + k0, Bf + 2048 + wbase);
  };

  STAGE(0, 0);
  int cur = 0;
  for (int k0 = 0; k0 < K; k0 += 32) {
    if (k0 + 32 < K) {
      STAGE(cur ^ 1, k0 + 32);                      // 4 next-tile loads in flight
      asm volatile("s_waitcnt vmcnt(4)" ::: "memory");  // cur tile landed
    } else {
      asm volatile("s_waitcnt vmcnt(0)" ::: "memory");
    }
    __builtin_amdgcn_s_barrier();
    frag_ab af[4], bfr[4];
#pragma unroll
    for (int i = 0; i < 4; ++i) {
      af[i]  = ld_cf4(&As[cur][0][0], wm + i * 16 + l16, quad);
      bfr[i] = ld_cf4(&Bs[cur][0][0], wn + i * 16 + l16, quad);
    }
#pragma unroll
    for (int i = 0; i < 4; ++i)
#pragma unroll
      for (int j = 0; j < 4; ++j)
        acc[i][j] = __builtin_amdgcn_mfma_f32_16x16x32_bf16(af[i], bfr[j], acc[i][j], 0, 0, 0);
    __builtin_amdgcn_s_barrier();
    cur ^= 1;
  }

#pragma unroll
  for (int i = 0; i < 4; ++i) {
#pragma unroll
    for (int r = 0; r < 4; ++r) {
      const int row = bm + wm + i * 16 + quad * 4 + r;
#pragma unroll
      for (int j = 0; j < 4; ++j) {
        const int col = bn + wn + j * 16 + l16;
        float v = acc[i][j][r];
        if (g.bias) v += g.bias[col];
        if (g.Cf) g.Cf[(size_t)row * N + col] = v;
        if (g.Cb) g.Cb[(size_t)row * N + col] = f2b(v);
      }
    }
  }
}

// 64x64 tile MFMA GEMM (4 waves 2x2, each 32x32)
// dbuf + counted vmcnt + conflict-free LDS layout
__global__ __launch_bounds__(256) void gemm64x64(GemmArgs ga, int M, int N, int K) {
  const GemmB g = ga.gb[blockIdx.z];
  const int bm = blockIdx.y * 64, bn = blockIdx.x * 64;
  __shared__ bf16_t As[2][64][32];
  __shared__ bf16_t Bs[2][64][32];
  const int tid = threadIdx.x;
  const int lane = tid & 63, w = tid >> 6;
  const int quad = lane >> 4, l16 = lane & 15;
  const int wm = (w >> 1) * 32, wn = (w & 1) * 32;
  const int wbase = w << 9;

  frag_cd acc[2][2];
#pragma unroll
  for (int i = 0; i < 2; ++i)
#pragma unroll
    for (int j = 0; j < 2; ++j)
#pragma unroll
      for (int r = 0; r < 4; ++r) acc[i][j][r] = 0.f;

  const int sup0 = 4 * w + (lane >> 4);
  const int tt0 = (lane & 15) ^ (sup0 & 15);
  const int row0 = sup0 * 4 + (tt0 >> 2), seg0 = tt0 & 3;
  const size_t aoff0 = (size_t)(bm + row0) * K + seg0 * 8;
  const size_t boff0 = (size_t)(bn + row0) * K + seg0 * 8;

  auto STAGE = [&](int buf, int k0) {
    gll16(g.A + aoff0 + k0, &As[buf][0][0] + wbase);
    gll16(g.Bm + boff0 + k0, &Bs[buf][0][0] + wbase);
  };

  STAGE(0, 0);
  int cur = 0;
  for (int k0 = 0; k0 < K; k0 += 32) {
    if (k0 + 32 < K) {
      STAGE(cur ^ 1, k0 + 32);                      // 2 next-tile loads in flight
      asm volatile("s_waitcnt vmcnt(2)" ::: "memory");  // cur tile landed
    } else {
      asm volatile("s_waitcnt vmcnt(0)" ::: "memory");
    }
    __builtin_amdgcn_s_barrier();
    frag_ab af[2], bfr[2];
#pragma unroll
    for (int i = 0; i < 2; ++i) {
      af[i]  = ld_cf4(&As[cur][0][0], wm + i * 16 + l16, quad);
      bfr[i] = ld_cf4(&Bs[cur][0][0], wn + i * 16 + l16, quad);
    }
#pragma unroll
    for (int i = 0; i < 2; ++i)
#pragma unroll
      for (int j = 0; j < 2; ++j)
        acc[i][j] = __builtin_amdgcn_mfma_f32_16x16x32_bf16(af[i], bfr[j], acc[i][j], 0, 0, 0);
    __builtin_amdgcn_s_barrier();
    cur ^= 1;
  }

#pragma unroll
  for (int i = 0; i < 2; ++i) {
#pragma unroll
    for (int r = 0; r < 4; ++r) {
      const int row = bm + wm + i * 16 + quad * 4 + r;
#pragma unroll
      for (int j = 0; j < 2; ++j) {
        const int col = bn + wn + j * 16 + l16;
        float v = acc[i][j][r];
        if (g.bias) v += g.bias[col];
        if (g.Cf) g.Cf[(size_t)row * N + col] = v;
        if (g.Cb) g.Cb[(size_t)row * N + col] = f2b(v);
      }
    }
  }
}

// xmean[b][d] = mean over L of X[b][l][d]
__global__ __launch_bounds__(256) void xmean_kernel(const float* __restrict__ X,
                                                    float* __restrict__ xmean) {
  const int d = blockIdx.x * 256 + threadIdx.x;
  const int b = blockIdx.z;
  const int l0 = blockIdx.y * 64;
  float s = 0.f;
  for (int l = l0; l < l0 + 64; ++l)
    s += X[((size_t)b * LL + l) * DD + d];
  atomicAdd(&xmean[b * DD + d], s * (1.f / (float)LL));
}

// scores: one wave per output
__global__ __launch_bounds__(256) void scores_gemm(const float* __restrict__ xmean,
                                                   const float* __restrict__ Wq,
                                                   const float* __restrict__ bq,
                                                   const float* __restrict__ Wk,
                                                   const float* __restrict__ bk,
                                                   float* __restrict__ scores) {
  const int w = threadIdx.x >> 6, lane = threadIdx.x & 63;
  const int idx = blockIdx.x * 4 + w;
  const int t = idx >> 11, b = (idx >> 10) & 1, i = idx & 1023;
  const float* W = t ? Wk : Wq;
  const float* bias = t ? bk : bq;
  const float* xm = xmean + b * DD;
  float sum = 0.f;
#pragma unroll
  for (int k = 0; k < 4; ++k) {
    float4 wv = *(const float4*)&W[(size_t)i * DD + k * 256 + lane * 4];
    float4 xv = *(const float4*)&xm[k * 256 + lane * 4];
    sum += wv.x * xv.x + wv.y * xv.y + wv.z * xv.z + wv.w * xv.w;
  }
  sum = waveSum(sum);
  if (lane == 0) scores[idx] = sum + bias[i];
}

// Bsum: 16 blocks, float4 LDS reads
__global__ __launch_bounds__(256) void bsum_kernel(const float* __restrict__ scores,
                                                   float* __restrict__ bsum) {
  __shared__ float sc[DD];
  const int z = blockIdx.x, jb = blockIdx.y, tid = threadIdx.x;
#pragma unroll
  for (int s = 0; s < 4; ++s) sc[tid + s * 256] = scores[z * DD + tid + s * 256];
  __syncthreads();
  const int j = jb * 256 + tid;
  const float si = sc[j];
  float s = 0.f;
  for (int m = 0; m < DD; m += 4) {
    float4 v = *(const float4*)&sc[m];
    s += fabsf(si - v.x) + fabsf(si - v.y) + fabsf(si - v.z) + fabsf(si - v.w);
  }
  bsum[z * DD + j] = s;
}

// P row + folded bias'
__global__ __launch_bounds__(256) void p_kernel(const float* __restrict__ scores,
                                                const float* __restrict__ bsum,
                                                const float* __restrict__ bq,
                                                const float* __restrict__ bk,
                                                bf16_t* __restrict__ Pq,
                                                bf16_t* __restrict__ Pk,
                                                float* __restrict__ bias4) {
  const int i = blockIdx.x;
  const int z = blockIdx.y;
  const int t = z >> 1, b = z & 1;
  const float* sc = scores + z * DD;
  const float* bs = bsum + z * DD;
  const float* bias = t ? bk : bq;
  const float scal = 1023.f - 2.f * (float)i;
  const int tid = threadIdx.x;
  __shared__ float redA[4], redB[4], redC[4];

  float lg[4], bb[4];
  float mx = -1e30f;
#pragma unroll
  for (int s = 0; s < 4; ++s) {
    const int j = tid + s * 256;
    lg[s] = sc[j] * scal - bs[j];
    bb[s] = bias[j];
    mx = fmaxf(mx, lg[s]);
  }
  mx = waveMax(mx);
  if ((tid & 63) == 0) redA[tid >> 6] = mx;
  __syncthreads();
  const float M = fmaxf(fmaxf(redA[0], redA[1]), fmaxf(redA[2], redA[3]));
  float sum = 0.f, dot = 0.f;
#pragma unroll
  for (int s = 0; s < 4; ++s) {
    lg[s] = __expf(lg[s] - M);
    sum += lg[s];
    dot += lg[s] * bb[s];
  }
  sum = waveSum(sum); dot = waveSum(dot);
  if ((tid & 63) == 0) { redB[tid >> 6] = sum; redC[tid >> 6] = dot; }
  __syncthreads();
  const float inv = 1.f / (redB[0] + redB[1] + redB[2] + redB[3]);
  bf16_t* P = (t ? Pk : Pq) + ((size_t)b << 20) + (size_t)i * DD;
#pragma unroll
  for (int s = 0; s < 4; ++s) P[tid + s * 256] = f2b(lg[s] * inv);
  if (tid == 0)
    bias4[t * 2048 + b * 1024 + i] = (redC[0] + redC[1] + redC[2] + redC[3]) * inv;
}

// merged euler (blocks 0..16383, q scaled by QSCALE) + V transpose (16384..)
// V transpose applies the 32x32x16 k-slot permutation: within each 16-key
// block of L, output position order is [0-3, 8-11, 4-7, 12-15] (bit2<->bit3
// involution), so attn's PV B-frags read contiguous b128.
__global__ __launch_bounds__(256) void euler_transv(bf16_t* __restrict__ qs,
                                                    bf16_t* __restrict__ ks,
                                                    const float* __restrict__ delta,
                                                    const float* __restrict__ beul,
                                                    const float* __restrict__ lsc,
                                                    const bf16_t* __restrict__ vb,
                                                    bf16_t* __restrict__ vbT) {
  __shared__ bf16_t T[64][72];
  const int bid = blockIdx.x;
  const int tid = threadIdx.x;
  if (bid < 16384) {
    const int isq = (bid < 8192);
    unsigned int* buf = (unsigned int*)(isq ? qs : ks);
    const int idx = (isq ? bid : bid - 8192) * 256 + tid;
    const int c = idx & 511;
    const size_t n = idx >> 9;
    const unsigned int u = buf[n * 512 + c];
    const float r = b2f((bf16_t)(u & 0xffffu));
    const float p = b2f((bf16_t)(u >> 16));
    float lam = sqrtf(r * r + p * p + 1e-6f);
    float th = atan2f(p, r) * delta[c];
    if (isq) th += beul[c];
    lam *= __expf(fminf(fmaxf(lsc[c], -5.f), 5.f));
    if (isq) lam *= QSCALE;    // fold attention scale into q (q only feeds attn)
    float sn, cs;
    __sincosf(th, &sn, &cs);
    buf[n * 512 + c] = ((unsigned int)f2b(lam * sn) << 16) | (unsigned int)f2b(lam * cs);
    return;
  }
  const int tb = bid - 16384;                 // 0..1023: (32, 16, 2)
  const int l0 = (tb & 31) * 64, d0 = ((tb >> 5) & 15) * 64, b = tb >> 9;
  for (int i = tid; i < 512; i += 256) {
    const int r = i >> 3, seg = i & 7;
    uint4 v = *(const uint4*)&vb[((size_t)b * LL + l0 + r) * DD + d0 + seg * 8];
    const bf16_t* vs = (const bf16_t*)&v;
#pragma unroll
    for (int j = 0; j < 8; ++j) T[seg * 8 + j][r] = vs[j];
  }
  __syncthreads();
  for (int i = tid; i < 512; i += 256) {
    const int r = i >> 3, seg = i & 7;
    // permuted gather: positions seg*8..+8 hold keys {base..base+3, base+8..+11}
    const int kb = (seg >> 1) * 16 + (seg & 1) * 4;
    uint2 lo = *(const uint2*)&T[r][kb];
    uint2 hi2 = *(const uint2*)&T[r][kb + 8];
    uint4 o; o.x = lo.x; o.y = lo.y; o.z = hi2.x; o.w = hi2.y;
    *(uint4*)&vbT[((size_t)b * DD + d0 + r) * LL + l0 + seg * 8] = o;
  }
}

// ---------------------------------------------------------------------------
// Flash attention v10 (r24, proven 49.6us): 512 blocks x 256 thr,
// 4 waves x 32 queries (32x32x16), P in regs, key-permuted V,
// conflict-free K/V layout, dbuf + vmcnt(4) + two barriers.
// ---------------------------------------------------------------------------
__global__ __launch_bounds__(256) void attn_kernel(const bf16_t* __restrict__ Q,
                                                   const bf16_t* __restrict__ Kt,
                                                   const bf16_t* __restrict__ VT,
                                                   bf16_t* __restrict__ O) {
  const int bid = blockIdx.x;
  const int swz = (bid & 7) * 64 + (bid >> 3);    // bijective, 64 blocks/XCD
  const int g = swz >> 4;                         // 4 bh-groups per XCD
  const int qt = swz & 15;
  const int b = g >> 4, h = g & 15;
  const int q0 = qt * 128;
  const int tid = threadIdx.x, w = tid >> 6, lane = tid & 63;
  const int hi = lane >> 5, l31 = lane & 31;

  __shared__ bf16_t Ks[2][64 * 64];
  __shared__ bf16_t Vs[2][64 * 64];

  const size_t base = (size_t)b * LL * DD + (size_t)h * DH;
  const size_t vtb = (size_t)(b * DD + h * DH) * LL;

  // Q fragments straight to registers (q pre-scaled by QSCALE at euler)
  // B-frag 32x32x16: col=lane&31 (query), k = hi*8+j (d)
  frag_ab bq[4];
#pragma unroll
  for (int kd = 0; kd < 4; ++kd)
    bq[kd] = *(const frag_ab*)
        &Q[base + (size_t)(q0 + w * 32 + l31) * DD + kd * 16 + hi * 8];

  // constant ones-column B-frag: col 0 => lanes with l31==0 hold 8x 1.0
  frag_ab bone;
  {
    const short o = (l31 == 0) ? (short)0x3F80 : (short)0;
#pragma unroll
    for (int j = 0; j < 8; ++j) bone[j] = o;
  }

  f32x16 o_[2], l5;
#pragma unroll
  for (int i = 0; i < 16; ++i) { o_[0][i] = 0.f; o_[1][i] = 0.f; l5[i] = 0.f; }

  // STAGE decode for conflict-free layout
  const int sup_l = lane >> 4;
  const int sl15 = lane & 15;

  auto STAGE = [&](int buf, int kt) {
#pragma unroll
    for (int t = 0; t < 2; ++t) {
      const int supb = w * 8 + t * 4;
      const int sup = supb + sup_l;
      const int tt = sl15 ^ (sup & 15);
      const int row = sup * 2 + (tt >> 3);
      const int ch = tt & 7;
      gll16(Kt + base + (size_t)(kt * 64 + row) * DD + ch * 8,
            &Ks[buf][(w * 16 + t * 8) * 64]);
      gll16(VT + vtb + (size_t)row * LL + kt * 64 + ch * 8,
            &Vs[buf][(w * 16 + t * 8) * 64]);
    }
  };

  STAGE(0, 0);
  int cur = 0;
  const int NT = LL / 64;
  for (int kt = 0; kt < NT; ++kt) {
    if (kt + 1 < NT) {
      STAGE(cur ^ 1, kt + 1);                       // 4 next-tile loads in flight
      asm volatile("s_waitcnt vmcnt(4)" ::: "memory");  // cur tile landed
    } else {
      asm volatile("s_waitcnt vmcnt(0)" ::: "memory");
    }
    __builtin_amdgcn_s_barrier();                   // all waves staged cur

    const bf16_t* Kb = Ks[cur];
    const bf16_t* Vb = Vs[cur];

    // QK: S^T = K·Q^T + EOFF per 32-key half; P kept in registers.
    // D layout: col=l31 (query), row(reg r) = (r&3)+8*(r>>2)+4*hi (key)
    frag_ab pa[4];
#pragma unroll
    for (int s = 0; s < 2; ++s) {
      frag_ab ak[4];
#pragma unroll
      for (int kd = 0; kd < 4; ++kd)
        ak[kd] = ld_cf(Kb, s * 32 + l31, kd * 2 + hi);
      f32x16 z;
#pragma unroll
      for (int i = 0; i < 16; ++i) z[i] = EOFF;
#pragma unroll
      for (int kd = 0; kd < 4; ++kd)
        z = __builtin_amdgcn_mfma_f32_32x32x16_bf16(ak[kd], bq[kd], z, 0, 0, 0);
#pragma unroll
      for (int t = 0; t < 2; ++t) {
        float p[8];
#pragma unroll
        for (int j = 0; j < 8; ++j) p[j] = __builtin_amdgcn_exp2f(z[t * 8 + j]);
        pa[s * 2 + t] = pack8(p);   // A-frag kstep 2s+t: key(hi,j) matches V perm
      }
    }

    // l += P · ones (A-frags reused; MFMA pipe)
#pragma unroll
    for (int k = 0; k < 4; ++k)
      l5 = __builtin_amdgcn_mfma_f32_32x32x16_bf16(pa[k], bone, l5, 0, 0, 0);

    // O += P V  (V key-order pre-permuted in global => contiguous B-frags)
#pragma unroll
    for (int dt = 0; dt < 2; ++dt)
#pragma unroll
      for (int k = 0; k < 4; ++k) {
        frag_ab bv = ld_cf(Vb, dt * 32 + l31, k * 2 + hi);
        o_[dt] = __builtin_amdgcn_mfma_f32_32x32x16_bf16(pa[k], bv, o_[dt], 0, 0, 0);
      }

    __builtin_amdgcn_s_barrier();                   // all done reading cur
    cur ^= 1;
  }

  // l[q] lives at col 0 => lane hi*32, reg r (q = (r&3)+8*(r>>2)+4*hi)
  const int src = (lane >> 5) << 5;
  float lf[16];
#pragma unroll
  for (int r = 0; r < 16; ++r) lf[r] = 1.f / __shfl(l5[r], src);

#pragma unroll
  for (int dt = 0; dt < 2; ++dt)
#pragma unroll
    for (int r = 0; r < 16; ++r) {
      const int ql = (r & 3) + 8 * (r >> 2) + 4 * hi;
      O[base + (size_t)(q0 + w * 32 + ql) * DD + dt * 32 + l31] =
          f2b(o_[dt][r] * lf[r]);
    }
}

// layernorm(hidden(bf16) + X) * gamma + beta -> FP32 out
__global__ __launch_bounds__(256) void ln_kernel(const bf16_t* __restrict__ hidden,
                                                 const float* __restrict__ x0,
                                                 const float* __restrict__ gamma,
                                                 const float* __restrict__ beta,
                                                 float* __restrict__ out) {
  const int row = blockIdx.x;
  const int tid = threadIdx.x;
  __shared__ float red1[4], red2[4];
  float v[4];
  float s1 = 0.f, s2 = 0.f;
#pragma unroll
  for (int s = 0; s < 4; ++s) {
    const int c = tid + s * 256;
    const float x = b2f(hidden[(size_t)row * DD + c]) + x0[(size_t)row * DD + c];
    v[s] = x; s1 += x; s2 += x * x;
  }
  s1 = waveSum(s1); s2 = waveSum(s2);
  if ((tid & 63) == 0) { red1[tid >> 6] = s1; red2[tid >> 6] = s2; }
  __syncthreads();
  const float t1 = red1[0] + red1[1] + red1[2] + red1[3];
  const float t2 = red2[0] + red2[1] + red2[2] + red2[3];
  const float mu = t1 * (1.f / DD);
  const float var = t2 * (1.f / DD) - mu * mu;
  const float inv = rsqrtf(var + 1e-12f);
#pragma unroll
  for (int s = 0; s < 4; ++s) {
    const int c = tid + s * 256;
    out[(size_t)row * DD + c] = (v[s] - mu) * inv * gamma[c] + beta[c];
  }
}

// ---------------------------------------------------------------------------
extern "C" void kernel_launch(void* const* d_in, const int* in_sizes, int n_in,
                              void* d_out, int out_size, void* d_ws, size_t ws_size,
                              hipStream_t stream) {
  const float* X    = (const float*)d_in[0];
  const float* Wq   = (const float*)d_in[1];
  const float* bq   = (const float*)d_in[2];
  const float* Wk   = (const float*)d_in[3];
  const float* bk   = (const float*)d_in[4];
  const float* Wv   = (const float*)d_in[5];
  const float* bv   = (const float*)d_in[6];
  const float* Wd   = (const float*)d_in[7];
  const float* bd   = (const float*)d_in[8];
  const float* gam  = (const float*)d_in[9];
  const float* bet  = (const float*)d_in[10];
  const float* delt = (const float*)d_in[11];
  const float* beul = (const float*)d_in[12];
  const float* lsc  = (const float*)d_in[13];
  float* out = (float*)d_out;

  char* w = (char*)d_ws;
  const size_t MB = 1024ull * 1024ull;
  bf16_t* Xb  = (bf16_t*)(w + 0 * MB);    // 8MB
  bf16_t* Wvb = (bf16_t*)(w + 8 * MB);    // 2MB
  bf16_t* Wdb = (bf16_t*)(w + 10 * MB);   // 2MB
  bf16_t* WqT = (bf16_t*)(w + 12 * MB);   // 2MB
  bf16_t* WkT = (bf16_t*)(w + 14 * MB);   // 2MB
  bf16_t* Pq  = (bf16_t*)(w + 16 * MB);   // 4MB
  bf16_t* Pk  = (bf16_t*)(w + 20 * MB);   // 4MB
  bf16_t* Wp  = (bf16_t*)(w + 24 * MB);   // 8MB: W'q[2], W'k[2]
  bf16_t* vb  = (bf16_t*)(w + 32 * MB);   // 8MB  (dead after transpose)
  bf16_t* qs  = (bf16_t*)(w + 40 * MB);   // 8MB
  bf16_t* ks  = (bf16_t*)(w + 48 * MB);   // 8MB
  bf16_t* vbT = (bf16_t*)(w + 56 * MB);   // 8MB
  bf16_t* ctx = (bf16_t*)(w + 64 * MB);   // 8MB
  bf16_t* hid = (bf16_t*)(w + 24 * MB);   // 8MB bf16, overlays Wp (dead after attn)
  float*  xmean  = (float*)(w + 72 * MB);             // 8KB
  float*  scores = (float*)(w + 72 * MB + 16384);     // 16KB
  float*  bsum   = (float*)(w + 72 * MB + 32768);     // 16KB
  float*  bias4  = (float*)(w + 72 * MB + 49152);     // 16KB

  const size_t WSZ = (size_t)DD * DD;

  // 0) merged casts + xmean zero + Wq/Wk transpose (one launch)
  prep_cast<<<dim3(6657), 256, 0, stream>>>(X, Wv, Wd, Wq, Wk,
                                            Xb, Wvb, Wdb, WqT, WkT, xmean);

  // 1) scores via linearity (exact fp32)
  xmean_kernel<<<dim3(4, 32, 2), 256, 0, stream>>>(X, xmean);
  scores_gemm<<<dim3(1024), 256, 0, stream>>>(xmean, Wq, bq, Wk, bk, scores);

  // 2) neural sort P (+ folded bias')
  bsum_kernel<<<dim3(4, 4), 256, 0, stream>>>(scores, bsum);
  p_kernel<<<dim3(1024, 4), 256, 0, stream>>>(scores, bsum, bq, bk, Pq, Pk, bias4);

  // 3) W' = P · W  (gemm64x64: 1024 blocks, 4/CU)
  GemmArgs gw = {};
  gw.gb[0] = {Pq,       WqT, nullptr, nullptr, Wp};
  gw.gb[1] = {Pq + WSZ, WqT, nullptr, nullptr, Wp + WSZ};
  gw.gb[2] = {Pk,       WkT, nullptr, nullptr, Wp + 2 * WSZ};
  gw.gb[3] = {Pk + WSZ, WkT, nullptr, nullptr, Wp + 3 * WSZ};
  gemm64x64<<<dim3(16, 16, 4), 256, 0, stream>>>(gw, DD, DD, DD);

  // 4) qs/ks/vb (gemm128, 768 blocks, 3/CU, XCD-swizzled)
  const size_t XHALF = (size_t)LL * DD;
  GemmArgs gs = {};
  gs.gb[0] = {Xb,         Wp,           bias4,        nullptr, qs};
  gs.gb[1] = {Xb + XHALF, Wp + WSZ,     bias4 + 1024, nullptr, qs + XHALF};
  gs.gb[2] = {Xb,         Wp + 2 * WSZ, bias4 + 2048, nullptr, ks};
  gs.gb[3] = {Xb + XHALF, Wp + 3 * WSZ, bias4 + 3072, nullptr, ks + XHALF};
  gs.gb[4] = {Xb,         Wvb,          bv,           nullptr, vb};
  gs.gb[5] = {Xb + XHALF, Wvb,          bv,           nullptr, vb + XHALF};
  gemm128<<<dim3(8, 16, 6), 256, 0, stream>>>(gs, LL, DD, DD);

  // 5) euler (q pre-scaled) + V transpose (key-permuted), merged
  euler_transv<<<dim3(17408), 256, 0, stream>>>(qs, ks, delt, beul, lsc, vb, vbT);

  // 6) attention v10 (r24 proven: 512 blocks x 256 thr)
  attn_kernel<<<dim3(512), 256, 0, stream>>>(qs, ks, vbT, ctx);

  // 7) output projection (gemm64x64: 1024 blocks)
  GemmArgs g4 = {};
  g4.gb[0] = {ctx, Wdb, bd, nullptr, hid};
  gemm64x64<<<dim3(16, 64, 1), 256, 0, stream>>>(g4, BB * LL, DD, DD);

  // 8) layernorm + residual -> fp32
  ln_kernel<<<dim3(BB * LL), 256, 0, stream>>>(hid, X, gam, bet, out);
}